// Round 1
// baseline (3859.481 us; speedup 1.0000x reference)
//
#include <hip/hip_runtime.h>

static inline int ceil_div(long long a, long long b) { return (int)((a + b - 1) / b); }

__device__ __forceinline__ float lrelu(float t) { return t > 0.f ? t : 0.2f * t; }

// float atomic-max via int atomics (valid for arbitrary-sign IEEE floats)
__device__ __forceinline__ void atomicMaxFloat(float* addr, float val) {
  if (val >= 0.f) atomicMax((int*)addr, __float_as_int(val));
  else            atomicMin((unsigned int*)addr, __float_as_uint(val));
}

__device__ __forceinline__ void atomAddF(float* p, float v) {
  unsafeAtomicAdd(p, v);  // hardware global_atomic_add_f32 (no CAS loop)
}

// ---------------- GEMM + attention-score kernel ----------------
// h = X @ W  (X: [N,DIN], W: [DIN,DOUT] row-major), plus s_src = h.a_src, s_dst = h.a_dst
// Thread tile: 4 rows x 4 cols. Block covers ROWS rows x DOUT cols.
template<int DIN, int DOUT>
__launch_bounds__(256)
__global__ void gemm_att(const float* __restrict__ X, const float* __restrict__ Wm,
                         const float* __restrict__ avs, const float* __restrict__ avd,
                         float* __restrict__ H, float* __restrict__ Ss, float* __restrict__ Sd,
                         int N) {
  constexpr int TN = 4;
  constexpr int TX = DOUT / TN;       // 32 (DOUT=128) or 16 (DOUT=64)
  constexpr int TM = 4;
  constexpr int TY = 256 / TX;        // 8 or 16
  constexpr int ROWS = TY * TM;       // 32 or 64
  constexpr int KT = 32;
  __shared__ float Wl[KT][DOUT];
  __shared__ float xs[ROWS][KT + 1];

  const int t = threadIdx.x;
  const int tx = t % TX, ty = t / TX;
  const int base = blockIdx.x * ROWS;
  if (base >= N) return;

  float asv[TN], adv[TN];
#pragma unroll
  for (int j = 0; j < TN; j++) { asv[j] = avs[tx*TN + j]; adv[j] = avd[tx*TN + j]; }

  float acc[TM][TN];
#pragma unroll
  for (int r = 0; r < TM; r++)
#pragma unroll
    for (int j = 0; j < TN; j++) acc[r][j] = 0.f;

  for (int k0 = 0; k0 < DIN; k0 += KT) {
    __syncthreads();
    for (int idx = t; idx < KT * DOUT; idx += 256) {
      int ki = idx / DOUT, c = idx % DOUT;
      Wl[ki][c] = Wm[(size_t)(k0 + ki) * DOUT + c];
    }
    for (int idx = t; idx < ROWS * KT; idx += 256) {
      int r = idx / KT, ki = idx % KT;
      int n = base + r;
      xs[r][ki] = (n < N) ? X[(size_t)n * DIN + k0 + ki] : 0.f;
    }
    __syncthreads();
#pragma unroll
    for (int ki = 0; ki < KT; ki++) {
      const float4 wv = *(const float4*)&Wl[ki][tx * TN];
#pragma unroll
      for (int r = 0; r < TM; r++) {
        const float xv = xs[ty*TM + r][ki];
        acc[r][0] = fmaf(xv, wv.x, acc[r][0]);
        acc[r][1] = fmaf(xv, wv.y, acc[r][1]);
        acc[r][2] = fmaf(xv, wv.z, acc[r][2]);
        acc[r][3] = fmaf(xv, wv.w, acc[r][3]);
      }
    }
  }

  // epilogue: store H, reduce attention scores across the TX lane group
#pragma unroll
  for (int r = 0; r < TM; r++) {
    const int n = base + ty*TM + r;
    if (n < N) {
      float4 o = make_float4(acc[r][0], acc[r][1], acc[r][2], acc[r][3]);
      *(float4*)&H[(size_t)n * DOUT + tx * TN] = o;
    }
    float ps = acc[r][0]*asv[0] + acc[r][1]*asv[1] + acc[r][2]*asv[2] + acc[r][3]*asv[3];
    float pd = acc[r][0]*adv[0] + acc[r][1]*adv[1] + acc[r][2]*adv[2] + acc[r][3]*adv[3];
#pragma unroll
    for (int off = TX/2; off >= 1; off >>= 1) {
      ps += __shfl_down(ps, off);
      pd += __shfl_down(pd, off);
    }
    if (tx == 0 && n < N) { Ss[n] = ps; Sd[n] = pd; }
  }
}

// m[n] = leaky_relu(s_src[n] + s_dst[n])  (the self-loop score seeds the segment max)
__global__ void node_init(const float* __restrict__ Ss, const float* __restrict__ Sd,
                          float* __restrict__ mM, int N) {
  int n = blockIdx.x * blockDim.x + threadIdx.x;
  if (n < N) mM[n] = lrelu(Ss[n] + Sd[n]);
}

__global__ void edge_max(const int* __restrict__ src, const int* __restrict__ dstv,
                         const float* __restrict__ Ss, const float* __restrict__ Sd,
                         float* __restrict__ mM, int E) {
  int e = blockIdx.x * blockDim.x + threadIdx.x;
  if (e < E) {
    int s = src[e], d = dstv[e];
    atomicMaxFloat(&mM[d], lrelu(Ss[s] + Sd[d]));
  }
}

// One wave per edge: w = exp(e - m[dst]); denom[dst] += w; agg[dst] += h[src]*w
template<int DOUT>
__launch_bounds__(256)
__global__ void edge_agg(const int* __restrict__ src, const int* __restrict__ dstv,
                         const float* __restrict__ Ss, const float* __restrict__ Sd,
                         const float* __restrict__ mM, const float* __restrict__ H,
                         float* __restrict__ agg, float* __restrict__ dnm, int E) {
  const int lane = threadIdx.x & 63;
  const int wid = (int)((blockIdx.x * blockDim.x + threadIdx.x) >> 6);
  const int nw = (int)((gridDim.x * blockDim.x) >> 6);
  for (int e = wid; e < E; e += nw) {
    const int s = src[e], d = dstv[e];
    const float w = __expf(lrelu(Ss[s] + Sd[d]) - mM[d]);
    if (lane == 0) atomAddF(&dnm[d], w);
    if (DOUT == 128) {
      const float2 h2 = ((const float2*)(H + (size_t)s * 128))[lane];
      float* ap = agg + (size_t)d * 128 + 2 * lane;
      atomAddF(ap,     h2.x * w);
      atomAddF(ap + 1, h2.y * w);
    } else {
      const float hv = H[(size_t)s * DOUT + lane];
      atomAddF(agg + (size_t)d * DOUT + lane, hv * w);
    }
  }
}

// out[n,k] = (agg[n,k] + h[n,k]*w_self) / (denom[n] + w_self) + b[k]
template<int DOUT>
__global__ void finalize(const float* __restrict__ H, const float* __restrict__ aggIn,
                         const float* __restrict__ Ss, const float* __restrict__ Sd,
                         const float* __restrict__ mM, const float* __restrict__ dnm,
                         const float* __restrict__ b, float* __restrict__ out, int N) {
  int idx = blockIdx.x * blockDim.x + threadIdx.x;
  if (idx >= N * DOUT) return;
  int n = idx / DOUT, k = idx % DOUT;
  float ws = __expf(lrelu(Ss[n] + Sd[n]) - mM[n]);
  float inv = 1.f / (dnm[n] + ws);
  out[idx] = (aggIn[idx] + H[idx] * ws) * inv + b[k];
}

// column-wise mean over N rows of a [N,64] matrix
__global__ void mean64(const float* __restrict__ Hf, float* __restrict__ out, int N, float scale) {
  __shared__ float sm[256];
  const int col = threadIdx.x & 63;
  const int seg = threadIdx.x >> 6;          // 0..3
  const int stride = gridDim.x * 4;
  float s = 0.f;
  for (int n = blockIdx.x * 4 + seg; n < N; n += stride) s += Hf[(size_t)n * 64 + col];
  sm[threadIdx.x] = s;
  __syncthreads();
  if (seg == 0) {
    float tot = sm[col] + sm[64 + col] + sm[128 + col] + sm[192 + col];
    atomAddF(&out[col], tot * scale);
  }
}

template<int DIN, int DOUT>
static void run_layer(const float* X, const float* Wm, const float* avs, const float* avd,
                      const float* b, const int* src, const int* dstv, int N, int E,
                      float* H, float* AGG, float* Ss, float* Sd, float* mM, float* dnm,
                      hipStream_t stream) {
  constexpr int TX = DOUT / 4;
  constexpr int ROWS = (256 / TX) * 4;
  gemm_att<DIN, DOUT><<<ceil_div(N, ROWS), 256, 0, stream>>>(X, Wm, avs, avd, H, Ss, Sd, N);
  node_init<<<ceil_div(N, 256), 256, 0, stream>>>(Ss, Sd, mM, N);
  hipMemsetAsync(AGG, 0, (size_t)N * DOUT * sizeof(float), stream);
  hipMemsetAsync(dnm, 0, (size_t)N * sizeof(float), stream);
  edge_max<<<ceil_div(E, 256), 256, 0, stream>>>(src, dstv, Ss, Sd, mM, E);
  edge_agg<DOUT><<<2048, 256, 0, stream>>>(src, dstv, Ss, Sd, mM, H, AGG, dnm, E);
  finalize<DOUT><<<ceil_div((long long)N * DOUT, 256), 256, 0, stream>>>(H, AGG, Ss, Sd, mM, dnm, b, AGG, N);
}

extern "C" void kernel_launch(void* const* d_in, const int* in_sizes, int n_in,
                              void* d_out, int out_size, void* d_ws, size_t ws_size,
                              hipStream_t stream) {
  const float* x   = (const float*)d_in[0];
  const int*   ei  = (const int*)d_in[1];
  const float* W1  = (const float*)d_in[2];
  const float* as1 = (const float*)d_in[3];
  const float* ad1 = (const float*)d_in[4];
  const float* b1  = (const float*)d_in[5];
  const float* W2  = (const float*)d_in[6];
  const float* as2 = (const float*)d_in[7];
  const float* ad2 = (const float*)d_in[8];
  const float* b2  = (const float*)d_in[9];
  const float* W3  = (const float*)d_in[10];
  const float* as3 = (const float*)d_in[11];
  const float* ad3 = (const float*)d_in[12];
  const float* b3  = (const float*)d_in[13];

  const int N = in_sizes[0] / 128;
  const int E = in_sizes[1] / 2;
  const int* src  = ei;        // edge_idx[0]
  const int* dstv = ei + E;    // edge_idx[1]

  float* p = (float*)d_ws;
  float* bufH = p; p += (size_t)N * 128;   // h of current layer
  float* bufA = p; p += (size_t)N * 128;   // agg/out ping
  float* bufB = p; p += (size_t)N * 128;   // agg/out pong
  float* Ss   = p; p += N;
  float* Sd   = p; p += N;
  float* mM   = p; p += N;
  float* dnm  = p; p += N;

  // layer 1: x -> bufA ; layer 2: bufA -> bufB ; layer 3: bufB -> bufA
  run_layer<128, 128>(x,    W1, as1, ad1, b1, src, dstv, N, E, bufH, bufA, Ss, Sd, mM, dnm, stream);
  run_layer<128, 128>(bufA, W2, as2, ad2, b2, src, dstv, N, E, bufH, bufB, Ss, Sd, mM, dnm, stream);
  run_layer<128, 64> (bufB, W3, as3, ad3, b3, src, dstv, N, E, bufH, bufA, Ss, Sd, mM, dnm, stream);

  hipMemsetAsync(d_out, 0, 64 * sizeof(float), stream);
  mean64<<<256, 256, 0, stream>>>(bufA, (float*)d_out, N, 1.0f / (float)N);
}

// Round 2
// 799.407 us; speedup vs baseline: 4.8279x; 4.8279x over previous
//
#include <hip/hip_runtime.h>

static inline int ceil_div(long long a, long long b) { return (int)((a + b - 1) / b); }

__device__ __forceinline__ float lrelu(float t) { return t > 0.f ? t : 0.2f * t; }

__device__ __forceinline__ void atomAddF(float* p, float v) {
  unsafeAtomicAdd(p, v);  // hardware global_atomic_add_f32
}

// ---------------- GEMM + attention-score kernel (unchanged from R1) ----------------
template<int DIN, int DOUT>
__launch_bounds__(256)
__global__ void gemm_att(const float* __restrict__ X, const float* __restrict__ Wm,
                         const float* __restrict__ avs, const float* __restrict__ avd,
                         float* __restrict__ H, float* __restrict__ Ss, float* __restrict__ Sd,
                         int N) {
  constexpr int TN = 4;
  constexpr int TX = DOUT / TN;
  constexpr int TM = 4;
  constexpr int TY = 256 / TX;
  constexpr int ROWS = TY * TM;
  constexpr int KT = 32;
  __shared__ float Wl[KT][DOUT];
  __shared__ float xs[ROWS][KT + 1];

  const int t = threadIdx.x;
  const int tx = t % TX, ty = t / TX;
  const int base = blockIdx.x * ROWS;
  if (base >= N) return;

  float asv[TN], adv[TN];
#pragma unroll
  for (int j = 0; j < TN; j++) { asv[j] = avs[tx*TN + j]; adv[j] = avd[tx*TN + j]; }

  float acc[TM][TN];
#pragma unroll
  for (int r = 0; r < TM; r++)
#pragma unroll
    for (int j = 0; j < TN; j++) acc[r][j] = 0.f;

  for (int k0 = 0; k0 < DIN; k0 += KT) {
    __syncthreads();
    for (int idx = t; idx < KT * DOUT; idx += 256) {
      int ki = idx / DOUT, c = idx % DOUT;
      Wl[ki][c] = Wm[(size_t)(k0 + ki) * DOUT + c];
    }
    for (int idx = t; idx < ROWS * KT; idx += 256) {
      int r = idx / KT, ki = idx % KT;
      int n = base + r;
      xs[r][ki] = (n < N) ? X[(size_t)n * DIN + k0 + ki] : 0.f;
    }
    __syncthreads();
#pragma unroll
    for (int ki = 0; ki < KT; ki++) {
      const float4 wv = *(const float4*)&Wl[ki][tx * TN];
#pragma unroll
      for (int r = 0; r < TM; r++) {
        const float xv = xs[ty*TM + r][ki];
        acc[r][0] = fmaf(xv, wv.x, acc[r][0]);
        acc[r][1] = fmaf(xv, wv.y, acc[r][1]);
        acc[r][2] = fmaf(xv, wv.z, acc[r][2]);
        acc[r][3] = fmaf(xv, wv.w, acc[r][3]);
      }
    }
  }

#pragma unroll
  for (int r = 0; r < TM; r++) {
    const int n = base + ty*TM + r;
    if (n < N) {
      float4 o = make_float4(acc[r][0], acc[r][1], acc[r][2], acc[r][3]);
      *(float4*)&H[(size_t)n * DOUT + tx * TN] = o;
    }
    float ps = acc[r][0]*asv[0] + acc[r][1]*asv[1] + acc[r][2]*asv[2] + acc[r][3]*asv[3];
    float pd = acc[r][0]*adv[0] + acc[r][1]*adv[1] + acc[r][2]*adv[2] + acc[r][3]*adv[3];
#pragma unroll
    for (int off = TX/2; off >= 1; off >>= 1) {
      ps += __shfl_down(ps, off);
      pd += __shfl_down(pd, off);
    }
    if (tx == 0 && n < N) { Ss[n] = ps; Sd[n] = pd; }
  }
}

// ---------------- CSR build (once per launch, reused by all 3 layers) ----------------
__global__ void hist_k(const int* __restrict__ dstv, int* __restrict__ cnt, int E) {
  int i = blockIdx.x * blockDim.x + threadIdx.x;
  if (i < E) atomicAdd(&cnt[dstv[i]], 1);
}

// block sums over 1024-element chunks
__global__ void scan_p1(const int* __restrict__ cnt, int* __restrict__ bsum, int N) {
  __shared__ int sm[256];
  const int b = blockIdx.x;
  int s = 0;
  for (int i = threadIdx.x; i < 1024; i += 256) {
    int idx = b * 1024 + i;
    s += (idx < N) ? cnt[idx] : 0;
  }
  sm[threadIdx.x] = s; __syncthreads();
  for (int off = 128; off; off >>= 1) {
    if (threadIdx.x < off) sm[threadIdx.x] += sm[threadIdx.x + off];
    __syncthreads();
  }
  if (threadIdx.x == 0) bsum[b] = sm[0];
}

// single-block exclusive scan of block sums (NB <= 1024); also writes rowptr[N]=E
__global__ void scan_p2(const int* __restrict__ bsum, int* __restrict__ bofs,
                        int NB, int* __restrict__ rowptr_N, int E) {
  __shared__ int sm[1024];
  const int t = threadIdx.x;
  const int v0 = (t < NB) ? bsum[t] : 0;
  sm[t] = v0; __syncthreads();
  for (int off = 1; off < 1024; off <<= 1) {
    int v = (t >= off) ? sm[t - off] : 0;
    __syncthreads();
    sm[t] += v;
    __syncthreads();
  }
  if (t < NB) bofs[t] = sm[t] - v0;   // exclusive
  if (t == 0) *rowptr_N = E;
}

// per-chunk exclusive scan + block offset -> rowptr
__global__ void scan_p3(const int* __restrict__ cnt, const int* __restrict__ bofs,
                        int* __restrict__ rowptr, int N) {
  __shared__ int sm[1024];
  const int t = threadIdx.x;
  const int idx = blockIdx.x * 1024 + t;
  const int v = (idx < N) ? cnt[idx] : 0;
  sm[t] = v; __syncthreads();
  for (int off = 1; off < 1024; off <<= 1) {
    int u = (t >= off) ? sm[t - off] : 0;
    __syncthreads();
    sm[t] += u;
    __syncthreads();
  }
  if (idx < N) rowptr[idx] = sm[t] - v + bofs[blockIdx.x];
}

__global__ void scatter_k(const int* __restrict__ src, const int* __restrict__ dstv,
                          const int* __restrict__ rowptr, int* __restrict__ cur,
                          int* __restrict__ srcs, int E) {
  int i = blockIdx.x * blockDim.x + threadIdx.x;
  if (i < E) {
    int d = dstv[i];
    int pos = rowptr[d] + atomicAdd(&cur[d], 1);
    srcs[pos] = src[i];
  }
}

// ---------------- fused per-dst gather: softmax + weighted aggregate + bias ----------------
// one wave per destination node
template<int DOUT>
__launch_bounds__(256)
__global__ void node_gather(const int* __restrict__ rowptr, const int* __restrict__ srcs,
                            const float* __restrict__ Ss, const float* __restrict__ Sd,
                            const float* __restrict__ H, const float* __restrict__ b,
                            float* __restrict__ out, int N) {
  const int lane = threadIdx.x & 63;
  const int node = (int)((blockIdx.x * (unsigned)blockDim.x + threadIdx.x) >> 6);
  if (node >= N) return;
  const int r0 = rowptr[node], r1 = rowptr[node + 1];
  const int deg = r1 - r0;
  const float sd = Sd[node];
  const float eself = lrelu(Ss[node] + sd);
  float m = eself;

  // segment max (exact, matching reference)
  float e_reg = -1e30f; int s_reg = node;
  if (deg <= 64) {
    if (lane < deg) { s_reg = srcs[r0 + lane]; e_reg = lrelu(Ss[s_reg] + sd); }
    float mx = e_reg;
#pragma unroll
    for (int off = 32; off; off >>= 1) mx = fmaxf(mx, __shfl_xor(mx, off));
    m = fmaxf(m, mx);
  } else {
    for (int base0 = 0; base0 < deg; base0 += 64) {
      int j = base0 + lane;
      float ee = -1e30f;
      if (j < deg) { int ss = srcs[r0 + j]; ee = lrelu(Ss[ss] + sd); }
#pragma unroll
      for (int off = 32; off; off >>= 1) ee = fmaxf(ee, __shfl_xor(ee, off));
      m = fmaxf(m, ee);
    }
  }

  const float wself = __expf(eself - m);
  constexpr int PL = DOUT / 64;    // floats per lane (2 for 128, 1 for 64)
  float acc[PL];
  {
    const float* hp = H + (size_t)node * DOUT + PL * lane;
#pragma unroll
    for (int c = 0; c < PL; c++) acc[c] = hp[c] * wself;
  }
  float lsum = 0.f;  // per-lane partial of edge weights

  for (int base0 = 0; base0 < deg; base0 += 64) {
    const int j = base0 + lane;
    float w = 0.f; int sj = node;
    if (deg <= 64) {
      if (lane < deg) { sj = s_reg; w = __expf(e_reg - m); }
    } else if (j < deg) {
      sj = srcs[r0 + j];
      w = __expf(lrelu(Ss[sj] + sd) - m);
    }
    lsum += w;
    const int cnt = min(64, deg - base0);
    int t = 0;
    for (; t + 4 <= cnt; t += 4) {
      int s0 = __shfl(sj, t),   s1 = __shfl(sj, t+1);
      int s2 = __shfl(sj, t+2), s3 = __shfl(sj, t+3);
      float w0 = __shfl(w, t),   w1 = __shfl(w, t+1);
      float w2 = __shfl(w, t+2), w3 = __shfl(w, t+3);
      const float* p0 = H + (size_t)s0 * DOUT + PL * lane;
      const float* p1 = H + (size_t)s1 * DOUT + PL * lane;
      const float* p2 = H + (size_t)s2 * DOUT + PL * lane;
      const float* p3 = H + (size_t)s3 * DOUT + PL * lane;
      if (PL == 2) {
        float2 a0 = *(const float2*)p0, a1 = *(const float2*)p1;
        float2 a2 = *(const float2*)p2, a3 = *(const float2*)p3;
        acc[0] += a0.x*w0 + a1.x*w1 + a2.x*w2 + a3.x*w3;
        acc[1] += a0.y*w0 + a1.y*w1 + a2.y*w2 + a3.y*w3;
      } else {
        acc[0] += p0[0]*w0 + p1[0]*w1 + p2[0]*w2 + p3[0]*w3;
      }
    }
    for (; t < cnt; t++) {
      int st = __shfl(sj, t); float wt = __shfl(w, t);
      const float* pp = H + (size_t)st * DOUT + PL * lane;
#pragma unroll
      for (int c = 0; c < PL; c++) acc[c] += pp[c] * wt;
    }
  }

#pragma unroll
  for (int off = 32; off; off >>= 1) lsum += __shfl_xor(lsum, off);
  const float inv = 1.f / (lsum + wself);
  float* op = out + (size_t)node * DOUT + PL * lane;
#pragma unroll
  for (int c = 0; c < PL; c++) op[c] = acc[c] * inv + b[PL * lane + c];
}

// column-wise mean over N rows of a [N,64] matrix
__global__ void mean64(const float* __restrict__ Hf, float* __restrict__ out, int N, float scale) {
  __shared__ float sm[256];
  const int col = threadIdx.x & 63;
  const int seg = threadIdx.x >> 6;
  const int stride = gridDim.x * 4;
  float s = 0.f;
  for (int n = blockIdx.x * 4 + seg; n < N; n += stride) s += Hf[(size_t)n * 64 + col];
  sm[threadIdx.x] = s;
  __syncthreads();
  if (seg == 0) {
    float tot = sm[col] + sm[64 + col] + sm[128 + col] + sm[192 + col];
    atomAddF(&out[col], tot * scale);
  }
}

template<int DIN, int DOUT>
static void run_layer(const float* X, const float* Wm, const float* avs, const float* avd,
                      const float* b, const int* rowptr, const int* srcs, int N,
                      float* H, float* OUT, float* Ss, float* Sd, hipStream_t stream) {
  constexpr int TX = DOUT / 4;
  constexpr int ROWS = (256 / TX) * 4;
  gemm_att<DIN, DOUT><<<ceil_div(N, ROWS), 256, 0, stream>>>(X, Wm, avs, avd, H, Ss, Sd, N);
  node_gather<DOUT><<<ceil_div((long long)N * 64, 256), 256, 0, stream>>>(
      rowptr, srcs, Ss, Sd, H, b, OUT, N);
}

extern "C" void kernel_launch(void* const* d_in, const int* in_sizes, int n_in,
                              void* d_out, int out_size, void* d_ws, size_t ws_size,
                              hipStream_t stream) {
  const float* x   = (const float*)d_in[0];
  const int*   ei  = (const int*)d_in[1];
  const float* W1  = (const float*)d_in[2];
  const float* as1 = (const float*)d_in[3];
  const float* ad1 = (const float*)d_in[4];
  const float* b1  = (const float*)d_in[5];
  const float* W2  = (const float*)d_in[6];
  const float* as2 = (const float*)d_in[7];
  const float* ad2 = (const float*)d_in[8];
  const float* b2  = (const float*)d_in[9];
  const float* W3  = (const float*)d_in[10];
  const float* as3 = (const float*)d_in[11];
  const float* ad3 = (const float*)d_in[12];
  const float* b3  = (const float*)d_in[13];

  const int N = in_sizes[0] / 128;
  const int E = in_sizes[1] / 2;
  const int* src  = ei;        // edge_idx[0]
  const int* dstv = ei + E;    // edge_idx[1]
  const int NB = ceil_div(N, 1024);

  float* p = (float*)d_ws;
  float* bufH = p; p += (size_t)N * 128;   // h of current layer
  float* bufA = p; p += (size_t)N * 128;   // layer-out ping
  float* bufB = p; p += (size_t)N * 128;   // layer-out pong
  float* Ss   = p; p += N;
  float* Sd   = p; p += N;
  int* ip = (int*)p;
  int* cnt     = ip; ip += N;
  int* cur     = ip; ip += N;
  int* rowptr  = ip; ip += N + 1;
  int* bsum    = ip; ip += NB;
  int* bofs    = ip; ip += NB;
  int* srcs    = ip; ip += E;              // src ids sorted by dst (CSR payload)

  // ---- CSR build (dst-major), once; reused by all 3 layers ----
  hipMemsetAsync(cnt, 0, (size_t)N * sizeof(int), stream);
  hipMemsetAsync(cur, 0, (size_t)N * sizeof(int), stream);
  hist_k<<<ceil_div(E, 256), 256, 0, stream>>>(dstv, cnt, E);
  scan_p1<<<NB, 256, 0, stream>>>(cnt, bsum, N);
  scan_p2<<<1, 1024, 0, stream>>>(bsum, bofs, NB, rowptr + N, E);
  scan_p3<<<NB, 1024, 0, stream>>>(cnt, bofs, rowptr, N);
  scatter_k<<<ceil_div(E, 256), 256, 0, stream>>>(src, dstv, rowptr, cur, srcs, E);

  // ---- 3 GAT layers ----
  run_layer<128, 128>(x,    W1, as1, ad1, b1, rowptr, srcs, N, bufH, bufA, Ss, Sd, stream);
  run_layer<128, 128>(bufA, W2, as2, ad2, b2, rowptr, srcs, N, bufH, bufB, Ss, Sd, stream);
  run_layer<128, 64> (bufB, W3, as3, ad3, b3, rowptr, srcs, N, bufH, bufA, Ss, Sd, stream);

  hipMemsetAsync(d_out, 0, 64 * sizeof(float), stream);
  mean64<<<256, 256, 0, stream>>>(bufA, (float*)d_out, N, 1.0f / (float)N);
}

// Round 3
// 790.366 us; speedup vs baseline: 4.8832x; 1.0114x over previous
//
#include <hip/hip_runtime.h>

static inline int ceil_div(long long a, long long b) { return (int)((a + b - 1) / b); }

__device__ __forceinline__ float lrelu(float t) { return t > 0.f ? t : 0.2f * t; }

__device__ __forceinline__ void atomAddF(float* p, float v) {
  unsafeAtomicAdd(p, v);  // hardware global_atomic_add_f32
}

// ---------------- GEMM + attention-score kernel ----------------
template<int DIN, int DOUT>
__launch_bounds__(256)
__global__ void gemm_att(const float* __restrict__ X, const float* __restrict__ Wm,
                         const float* __restrict__ avs, const float* __restrict__ avd,
                         float* __restrict__ H, float* __restrict__ Ss, float* __restrict__ Sd,
                         int N) {
  constexpr int TN = 4;
  constexpr int TX = DOUT / TN;
  constexpr int TM = 4;
  constexpr int TY = 256 / TX;
  constexpr int ROWS = TY * TM;
  constexpr int KT = 32;
  __shared__ float Wl[KT][DOUT];
  __shared__ float xs[ROWS][KT + 1];

  const int t = threadIdx.x;
  const int tx = t % TX, ty = t / TX;
  const int base = blockIdx.x * ROWS;
  if (base >= N) return;

  float asv[TN], adv[TN];
#pragma unroll
  for (int j = 0; j < TN; j++) { asv[j] = avs[tx*TN + j]; adv[j] = avd[tx*TN + j]; }

  float acc[TM][TN];
#pragma unroll
  for (int r = 0; r < TM; r++)
#pragma unroll
    for (int j = 0; j < TN; j++) acc[r][j] = 0.f;

  for (int k0 = 0; k0 < DIN; k0 += KT) {
    __syncthreads();
    for (int idx = t; idx < KT * DOUT; idx += 256) {
      int ki = idx / DOUT, c = idx % DOUT;
      Wl[ki][c] = Wm[(size_t)(k0 + ki) * DOUT + c];
    }
    for (int idx = t; idx < ROWS * KT; idx += 256) {
      int r = idx / KT, ki = idx % KT;
      int n = base + r;
      xs[r][ki] = (n < N) ? X[(size_t)n * DIN + k0 + ki] : 0.f;
    }
    __syncthreads();
#pragma unroll
    for (int ki = 0; ki < KT; ki++) {
      const float4 wv = *(const float4*)&Wl[ki][tx * TN];
#pragma unroll
      for (int r = 0; r < TM; r++) {
        const float xv = xs[ty*TM + r][ki];
        acc[r][0] = fmaf(xv, wv.x, acc[r][0]);
        acc[r][1] = fmaf(xv, wv.y, acc[r][1]);
        acc[r][2] = fmaf(xv, wv.z, acc[r][2]);
        acc[r][3] = fmaf(xv, wv.w, acc[r][3]);
      }
    }
  }

#pragma unroll
  for (int r = 0; r < TM; r++) {
    const int n = base + ty*TM + r;
    if (n < N) {
      float4 o = make_float4(acc[r][0], acc[r][1], acc[r][2], acc[r][3]);
      *(float4*)&H[(size_t)n * DOUT + tx * TN] = o;
    }
    float ps = acc[r][0]*asv[0] + acc[r][1]*asv[1] + acc[r][2]*asv[2] + acc[r][3]*asv[3];
    float pd = acc[r][0]*adv[0] + acc[r][1]*adv[1] + acc[r][2]*adv[2] + acc[r][3]*adv[3];
#pragma unroll
    for (int off = TX/2; off >= 1; off >>= 1) {
      ps += __shfl_down(ps, off);
      pd += __shfl_down(pd, off);
    }
    if (tx == 0 && n < N) { Ss[n] = ps; Sd[n] = pd; }
  }
}

// ---------------- CSR build ----------------
__global__ void hist_k(const int* __restrict__ dstv, int* __restrict__ cnt, int E) {
  int i = blockIdx.x * blockDim.x + threadIdx.x;
  if (i < E) atomicAdd(&cnt[dstv[i]], 1);
}

__global__ void scan_p1(const int* __restrict__ cnt, int* __restrict__ bsum, int N) {
  __shared__ int sm[256];
  const int b = blockIdx.x;
  int s = 0;
  for (int i = threadIdx.x; i < 1024; i += 256) {
    int idx = b * 1024 + i;
    s += (idx < N) ? cnt[idx] : 0;
  }
  sm[threadIdx.x] = s; __syncthreads();
  for (int off = 128; off; off >>= 1) {
    if (threadIdx.x < off) sm[threadIdx.x] += sm[threadIdx.x + off];
    __syncthreads();
  }
  if (threadIdx.x == 0) bsum[b] = sm[0];
}

__global__ void scan_p2(const int* __restrict__ bsum, int* __restrict__ bofs,
                        int NB, int* __restrict__ rowptr_N, int E) {
  __shared__ int sm[1024];
  const int t = threadIdx.x;
  const int v0 = (t < NB) ? bsum[t] : 0;
  sm[t] = v0; __syncthreads();
  for (int off = 1; off < 1024; off <<= 1) {
    int v = (t >= off) ? sm[t - off] : 0;
    __syncthreads();
    sm[t] += v;
    __syncthreads();
  }
  if (t < NB) bofs[t] = sm[t] - v0;
  if (t == 0) *rowptr_N = E;
}

__global__ void scan_p3(const int* __restrict__ cnt, const int* __restrict__ bofs,
                        int* __restrict__ rowptr, int N) {
  __shared__ int sm[1024];
  const int t = threadIdx.x;
  const int idx = blockIdx.x * 1024 + t;
  const int v = (idx < N) ? cnt[idx] : 0;
  sm[t] = v; __syncthreads();
  for (int off = 1; off < 1024; off <<= 1) {
    int u = (t >= off) ? sm[t - off] : 0;
    __syncthreads();
    sm[t] += u;
    __syncthreads();
  }
  if (idx < N) rowptr[idx] = sm[t] - v + bofs[blockIdx.x];
}

__global__ void scatter_k(const int* __restrict__ src, const int* __restrict__ dstv,
                          const int* __restrict__ rowptr, int* __restrict__ cur,
                          int* __restrict__ srcs, int E) {
  int i = blockIdx.x * blockDim.x + threadIdx.x;
  if (i < E) {
    int d = dstv[i];
    int pos = rowptr[d] + atomicAdd(&cur[d], 1);
    srcs[pos] = src[i];
  }
}

// ---------------- fused per-dst gather: softmax + weighted aggregate + bias ----------------
// One wave per destination node. Multi-row gather: RPI rows per wave load-instruction
// (DOUT=128: 2 rows x 32 lanes x float4; DOUT=64: 4 rows x 16 lanes x float4).
template<int DOUT>
__launch_bounds__(256)
__global__ void node_gather(const int* __restrict__ rowptr, const int* __restrict__ srcs,
                            const float* __restrict__ Ss, const float* __restrict__ Sd,
                            const float* __restrict__ H, const float* __restrict__ b,
                            float* __restrict__ out, int N) {
  constexpr int LPR = DOUT / 4;   // lanes per row (32 or 16)
  constexpr int RPI = 64 / LPR;   // rows per load-instruction (2 or 4)
  const int lane = threadIdx.x & 63;
  const int sub  = lane / LPR;            // which row of the group this lane handles
  const int colb = (lane % LPR) * 4;      // float4 column base
  const int node = (int)((blockIdx.x * (unsigned)blockDim.x + threadIdx.x) >> 6);
  if (node >= N) return;
  const int r0 = rowptr[node], r1 = rowptr[node + 1];
  const int deg = r1 - r0;
  const float sd = Sd[node];
  const float eself = lrelu(Ss[node] + sd);

  // ---- pass 1: exact segment max over incoming edges (+ self) ----
  float m = eself;
  float e_reg = -1e30f; int s_reg = node;
  if (deg <= 64) {
    if (lane < deg) { s_reg = srcs[r0 + lane]; e_reg = lrelu(Ss[s_reg] + sd); }
    float mx = e_reg;
#pragma unroll
    for (int off = 32; off; off >>= 1) mx = fmaxf(mx, __shfl_xor(mx, off));
    m = fmaxf(m, mx);
  } else {
    for (int base0 = 0; base0 < deg; base0 += 64) {
      int j = base0 + lane;
      float ee = -1e30f;
      if (j < deg) { int ss = srcs[r0 + j]; ee = lrelu(Ss[ss] + sd); }
#pragma unroll
      for (int off = 32; off; off >>= 1) ee = fmaxf(ee, __shfl_xor(ee, off));
      m = fmaxf(m, ee);
    }
  }

  // ---- pass 2: weighted gather ----
  const float wself = __expf(eself - m);
  float4 acc = make_float4(0.f, 0.f, 0.f, 0.f);
  if (sub == 0) {
    const float4 hv = *(const float4*)(H + (size_t)node * DOUT + colb);
    acc.x = hv.x * wself; acc.y = hv.y * wself;
    acc.z = hv.z * wself; acc.w = hv.w * wself;
  }
  float lsum = 0.f;

  for (int base0 = 0; base0 < deg; base0 += 64) {
    // group metadata: per-lane src id + softmax weight, padded with w=0
    int sj; float w;
    if (deg <= 64) {
      sj = s_reg;
      w = (lane < deg) ? __expf(e_reg - m) : 0.f;
    } else {
      const int j = base0 + lane;
      if (j < deg) { sj = srcs[r0 + j]; w = __expf(lrelu(Ss[sj] + sd) - m); }
      else         { sj = node; w = 0.f; }
    }
    lsum += w;
    const int cnt = min(64, deg - base0);
#pragma unroll 1
    for (int t = 0; t < cnt; t += RPI * 4) {
      const int j0 = t + sub, j1 = t + RPI + sub, j2 = t + 2*RPI + sub, j3 = t + 3*RPI + sub;
      const int s0 = __shfl(sj, j0), s1 = __shfl(sj, j1);
      const int s2 = __shfl(sj, j2), s3 = __shfl(sj, j3);
      const float w0 = __shfl(w, j0), w1 = __shfl(w, j1);
      const float w2 = __shfl(w, j2), w3 = __shfl(w, j3);
      const float4 a0 = *(const float4*)(H + (size_t)s0 * DOUT + colb);
      const float4 a1 = *(const float4*)(H + (size_t)s1 * DOUT + colb);
      const float4 a2 = *(const float4*)(H + (size_t)s2 * DOUT + colb);
      const float4 a3 = *(const float4*)(H + (size_t)s3 * DOUT + colb);
      acc.x += a0.x*w0 + a1.x*w1 + a2.x*w2 + a3.x*w3;
      acc.y += a0.y*w0 + a1.y*w1 + a2.y*w2 + a3.y*w3;
      acc.z += a0.z*w0 + a1.z*w1 + a2.z*w2 + a3.z*w3;
      acc.w += a0.w*w0 + a1.w*w1 + a2.w*w2 + a3.w*w3;
    }
  }

  // reduce edge-weight sum across the wave
#pragma unroll
  for (int off = 32; off; off >>= 1) lsum += __shfl_xor(lsum, off);
  const float inv = 1.f / (lsum + wself);

  // combine the RPI row-accumulators down to lanes [0, LPR)
#pragma unroll
  for (int off = 32; off >= LPR; off >>= 1) {
    acc.x += __shfl_xor(acc.x, off);
    acc.y += __shfl_xor(acc.y, off);
    acc.z += __shfl_xor(acc.z, off);
    acc.w += __shfl_xor(acc.w, off);
  }
  if (lane < LPR) {
    const int c = lane * 4;
    float4 o;
    o.x = acc.x * inv + b[c];
    o.y = acc.y * inv + b[c + 1];
    o.z = acc.z * inv + b[c + 2];
    o.w = acc.w * inv + b[c + 3];
    *(float4*)(out + (size_t)node * DOUT + c) = o;
  }
}

// column-wise mean over N rows of a [N,64] matrix
__global__ void mean64(const float* __restrict__ Hf, float* __restrict__ out, int N, float scale) {
  __shared__ float sm[256];
  const int col = threadIdx.x & 63;
  const int seg = threadIdx.x >> 6;
  const int stride = gridDim.x * 4;
  float s = 0.f;
  for (int n = blockIdx.x * 4 + seg; n < N; n += stride) s += Hf[(size_t)n * 64 + col];
  sm[threadIdx.x] = s;
  __syncthreads();
  if (seg == 0) {
    float tot = sm[col] + sm[64 + col] + sm[128 + col] + sm[192 + col];
    atomAddF(&out[col], tot * scale);
  }
}

template<int DIN, int DOUT>
static void run_layer(const float* X, const float* Wm, const float* avs, const float* avd,
                      const float* b, const int* rowptr, const int* srcs, int N,
                      float* H, float* OUT, float* Ss, float* Sd, hipStream_t stream) {
  constexpr int TX = DOUT / 4;
  constexpr int ROWS = (256 / TX) * 4;
  gemm_att<DIN, DOUT><<<ceil_div(N, ROWS), 256, 0, stream>>>(X, Wm, avs, avd, H, Ss, Sd, N);
  node_gather<DOUT><<<ceil_div((long long)N * 64, 256), 256, 0, stream>>>(
      rowptr, srcs, Ss, Sd, H, b, OUT, N);
}

extern "C" void kernel_launch(void* const* d_in, const int* in_sizes, int n_in,
                              void* d_out, int out_size, void* d_ws, size_t ws_size,
                              hipStream_t stream) {
  const float* x   = (const float*)d_in[0];
  const int*   ei  = (const int*)d_in[1];
  const float* W1  = (const float*)d_in[2];
  const float* as1 = (const float*)d_in[3];
  const float* ad1 = (const float*)d_in[4];
  const float* b1  = (const float*)d_in[5];
  const float* W2  = (const float*)d_in[6];
  const float* as2 = (const float*)d_in[7];
  const float* ad2 = (const float*)d_in[8];
  const float* b2  = (const float*)d_in[9];
  const float* W3  = (const float*)d_in[10];
  const float* as3 = (const float*)d_in[11];
  const float* ad3 = (const float*)d_in[12];
  const float* b3  = (const float*)d_in[13];

  const int N = in_sizes[0] / 128;
  const int E = in_sizes[1] / 2;
  const int* src  = ei;
  const int* dstv = ei + E;
  const int NB = ceil_div(N, 1024);

  float* p = (float*)d_ws;
  float* bufH = p; p += (size_t)N * 128;
  float* bufA = p; p += (size_t)N * 128;
  float* bufB = p; p += (size_t)N * 128;
  float* Ss   = p; p += N;
  float* Sd   = p; p += N;
  int* ip = (int*)p;
  int* cnt     = ip; ip += N;
  int* cur     = ip; ip += N;
  int* rowptr  = ip; ip += N + 1;
  int* bsum    = ip; ip += NB;
  int* bofs    = ip; ip += NB;
  int* srcs    = ip; ip += E;

  // ---- CSR build (dst-major), once; reused by all 3 layers ----
  hipMemsetAsync(cnt, 0, (size_t)N * sizeof(int), stream);
  hipMemsetAsync(cur, 0, (size_t)N * sizeof(int), stream);
  hist_k<<<ceil_div(E, 256), 256, 0, stream>>>(dstv, cnt, E);
  scan_p1<<<NB, 256, 0, stream>>>(cnt, bsum, N);
  scan_p2<<<1, 1024, 0, stream>>>(bsum, bofs, NB, rowptr + N, E);
  scan_p3<<<NB, 1024, 0, stream>>>(cnt, bofs, rowptr, N);
  scatter_k<<<ceil_div(E, 256), 256, 0, stream>>>(src, dstv, rowptr, cur, srcs, E);

  // ---- 3 GAT layers ----
  run_layer<128, 128>(x,    W1, as1, ad1, b1, rowptr, srcs, N, bufH, bufA, Ss, Sd, stream);
  run_layer<128, 128>(bufA, W2, as2, ad2, b2, rowptr, srcs, N, bufH, bufB, Ss, Sd, stream);
  run_layer<128, 64> (bufB, W3, as3, ad3, b3, rowptr, srcs, N, bufH, bufA, Ss, Sd, stream);

  hipMemsetAsync(d_out, 0, 64 * sizeof(float), stream);
  mean64<<<256, 256, 0, stream>>>(bufA, (float*)d_out, N, 1.0f / (float)N);
}

// Round 4
// 665.239 us; speedup vs baseline: 5.8016x; 1.1881x over previous
//
#include <hip/hip_runtime.h>

static inline int ceil_div(long long a, long long b) { return (int)((a + b - 1) / b); }

__device__ __forceinline__ float lrelu(float t) { return t > 0.f ? t : 0.2f * t; }

__device__ __forceinline__ void atomAddF(float* p, float v) {
  unsafeAtomicAdd(p, v);  // hardware global_atomic_add_f32
}

// float -> bf16 with round-to-nearest-even
__device__ __forceinline__ unsigned short f2bf(float f) {
  unsigned int u = __float_as_uint(f);
  unsigned int r = ((u >> 16) & 1u) + 0x7fffu;
  return (unsigned short)((u + r) >> 16);
}

// ---------------- GEMM + attention-score kernel (bf16 H output) ----------------
template<int DIN, int DOUT>
__launch_bounds__(256)
__global__ void gemm_att(const float* __restrict__ X, const float* __restrict__ Wm,
                         const float* __restrict__ avs, const float* __restrict__ avd,
                         unsigned short* __restrict__ Hb, float* __restrict__ Ss,
                         float* __restrict__ Sd, int N) {
  constexpr int TN = 4;
  constexpr int TX = DOUT / TN;
  constexpr int TM = 4;
  constexpr int TY = 256 / TX;
  constexpr int ROWS = TY * TM;
  constexpr int KT = 32;
  __shared__ float Wl[KT][DOUT];
  __shared__ float xs[ROWS][KT + 1];

  const int t = threadIdx.x;
  const int tx = t % TX, ty = t / TX;
  const int base = blockIdx.x * ROWS;
  if (base >= N) return;

  float asv[TN], adv[TN];
#pragma unroll
  for (int j = 0; j < TN; j++) { asv[j] = avs[tx*TN + j]; adv[j] = avd[tx*TN + j]; }

  float acc[TM][TN];
#pragma unroll
  for (int r = 0; r < TM; r++)
#pragma unroll
    for (int j = 0; j < TN; j++) acc[r][j] = 0.f;

  for (int k0 = 0; k0 < DIN; k0 += KT) {
    __syncthreads();
    for (int idx = t; idx < KT * DOUT; idx += 256) {
      int ki = idx / DOUT, c = idx % DOUT;
      Wl[ki][c] = Wm[(size_t)(k0 + ki) * DOUT + c];
    }
    for (int idx = t; idx < ROWS * KT; idx += 256) {
      int r = idx / KT, ki = idx % KT;
      int n = base + r;
      xs[r][ki] = (n < N) ? X[(size_t)n * DIN + k0 + ki] : 0.f;
    }
    __syncthreads();
#pragma unroll
    for (int ki = 0; ki < KT; ki++) {
      const float4 wv = *(const float4*)&Wl[ki][tx * TN];
#pragma unroll
      for (int r = 0; r < TM; r++) {
        const float xv = xs[ty*TM + r][ki];
        acc[r][0] = fmaf(xv, wv.x, acc[r][0]);
        acc[r][1] = fmaf(xv, wv.y, acc[r][1]);
        acc[r][2] = fmaf(xv, wv.z, acc[r][2]);
        acc[r][3] = fmaf(xv, wv.w, acc[r][3]);
      }
    }
  }

#pragma unroll
  for (int r = 0; r < TM; r++) {
    const int n = base + ty*TM + r;
    if (n < N) {
      uint2 o;
      o.x = (unsigned int)f2bf(acc[r][0]) | ((unsigned int)f2bf(acc[r][1]) << 16);
      o.y = (unsigned int)f2bf(acc[r][2]) | ((unsigned int)f2bf(acc[r][3]) << 16);
      *(uint2*)&Hb[(size_t)n * DOUT + tx * TN] = o;
    }
    float ps = acc[r][0]*asv[0] + acc[r][1]*asv[1] + acc[r][2]*asv[2] + acc[r][3]*asv[3];
    float pd = acc[r][0]*adv[0] + acc[r][1]*adv[1] + acc[r][2]*adv[2] + acc[r][3]*adv[3];
#pragma unroll
    for (int off = TX/2; off >= 1; off >>= 1) {
      ps += __shfl_down(ps, off);
      pd += __shfl_down(pd, off);
    }
    if (tx == 0 && n < N) { Ss[n] = ps; Sd[n] = pd; }
  }
}

// ---------------- CSR build ----------------
__global__ void hist_rank(const int* __restrict__ dstv, int* __restrict__ cnt,
                          int* __restrict__ rank, int E) {
  int i = blockIdx.x * blockDim.x + threadIdx.x;
  if (i < E) rank[i] = atomicAdd(&cnt[dstv[i]], 1);
}

__global__ void scan_p1(const int* __restrict__ cnt, int* __restrict__ bsum, int N) {
  __shared__ int sm[256];
  const int b = blockIdx.x;
  int s = 0;
  for (int i = threadIdx.x; i < 1024; i += 256) {
    int idx = b * 1024 + i;
    s += (idx < N) ? cnt[idx] : 0;
  }
  sm[threadIdx.x] = s; __syncthreads();
  for (int off = 128; off; off >>= 1) {
    if (threadIdx.x < off) sm[threadIdx.x] += sm[threadIdx.x + off];
    __syncthreads();
  }
  if (threadIdx.x == 0) bsum[b] = sm[0];
}

__global__ void scan_p2(const int* __restrict__ bsum, int* __restrict__ bofs,
                        int NB, int* __restrict__ rowptr_N, int E) {
  __shared__ int sm[1024];
  const int t = threadIdx.x;
  const int v0 = (t < NB) ? bsum[t] : 0;
  sm[t] = v0; __syncthreads();
  for (int off = 1; off < 1024; off <<= 1) {
    int v = (t >= off) ? sm[t - off] : 0;
    __syncthreads();
    sm[t] += v;
    __syncthreads();
  }
  if (t < NB) bofs[t] = sm[t] - v0;
  if (t == 0) *rowptr_N = E;
}

__global__ void scan_p3(const int* __restrict__ cnt, const int* __restrict__ bofs,
                        int* __restrict__ rowptr, int N) {
  __shared__ int sm[1024];
  const int t = threadIdx.x;
  const int idx = blockIdx.x * 1024 + t;
  const int v = (idx < N) ? cnt[idx] : 0;
  sm[t] = v; __syncthreads();
  for (int off = 1; off < 1024; off <<= 1) {
    int u = (t >= off) ? sm[t - off] : 0;
    __syncthreads();
    sm[t] += u;
    __syncthreads();
  }
  if (idx < N) rowptr[idx] = sm[t] - v + bofs[blockIdx.x];
}

__global__ void scatter_k(const int* __restrict__ src, const int* __restrict__ dstv,
                          const int* __restrict__ rank, const int* __restrict__ rowptr,
                          int* __restrict__ srcs, int E) {
  int i = blockIdx.x * blockDim.x + threadIdx.x;
  if (i < E) srcs[rowptr[dstv[i]] + rank[i]] = src[i];
}

// ---------------- fused per-dst gather (bf16 H): softmax + weighted aggregate + bias ----
// One wave per destination node. bf16 rows: 8 elems (16 B) per lane,
// LPR lanes per row, RPI rows per load-instruction (1 KiB per wave-load).
template<int DOUT>
__launch_bounds__(256)
__global__ void node_gather(const int* __restrict__ rowptr, const int* __restrict__ srcs,
                            const float* __restrict__ Ss, const float* __restrict__ Sd,
                            const unsigned short* __restrict__ Hb, const float* __restrict__ b,
                            float* __restrict__ out, int N) {
  constexpr int LPR = DOUT / 8;   // lanes per row: 16 (128) or 8 (64)
  constexpr int RPI = 64 / LPR;   // rows per load-instruction: 4 or 8
  constexpr int MAIN = 16;        // edges per main-body iteration
  constexpr int NL = MAIN / RPI;  // loads per main-body iteration (4 or 2)
  const int lane = threadIdx.x & 63;
  const int sub  = lane / LPR;
  const int cole = (lane % LPR) * 8;   // element column base
  const int node = (int)((blockIdx.x * (unsigned)blockDim.x + threadIdx.x) >> 6);
  if (node >= N) return;
  const int r0 = rowptr[node], r1 = rowptr[node + 1];
  const int deg = r1 - r0;
  const float sd = Sd[node];
  const float eself = lrelu(Ss[node] + sd);

  // ---- pass 1: exact segment max ----
  float m = eself;
  float e_reg = -1e30f; int s_reg = node;
  if (deg <= 64) {
    if (lane < deg) { s_reg = srcs[r0 + lane]; e_reg = lrelu(Ss[s_reg] + sd); }
    float mx = e_reg;
#pragma unroll
    for (int off = 32; off; off >>= 1) mx = fmaxf(mx, __shfl_xor(mx, off));
    m = fmaxf(m, mx);
  } else {
    for (int base0 = 0; base0 < deg; base0 += 64) {
      int j = base0 + lane;
      float ee = -1e30f;
      if (j < deg) { int ss = srcs[r0 + j]; ee = lrelu(Ss[ss] + sd); }
#pragma unroll
      for (int off = 32; off; off >>= 1) ee = fmaxf(ee, __shfl_xor(ee, off));
      m = fmaxf(m, ee);
    }
  }

  // ---- pass 2: weighted gather ----
  const float wself = __expf(eself - m);
  float acc[8];
#pragma unroll
  for (int k = 0; k < 8; k++) acc[k] = 0.f;
  if (sub == 0) {
    const uint4 u = *(const uint4*)(Hb + (size_t)node * DOUT + cole);
    const unsigned int vk[4] = {u.x, u.y, u.z, u.w};
#pragma unroll
    for (int k = 0; k < 4; k++) {
      acc[2*k]   += __uint_as_float(vk[k] << 16) * wself;
      acc[2*k+1] += __uint_as_float(vk[k] & 0xffff0000u) * wself;
    }
  }
  float lsum = 0.f;

  for (int base0 = 0; base0 < deg; base0 += 64) {
    int sj; float w;
    if (deg <= 64) {
      sj = s_reg;
      w = (lane < deg) ? __expf(e_reg - m) : 0.f;
    } else {
      const int j = base0 + lane;
      if (j < deg) { sj = srcs[r0 + j]; w = __expf(lrelu(Ss[sj] + sd) - m); }
      else         { sj = node; w = 0.f; }
    }
    lsum += w;
    const int cnt = min(64, deg - base0);
    int t = 0;
    // main body: MAIN edges per iteration, NL wave-loads in flight
    for (; t + MAIN <= cnt; t += MAIN) {
      int ss[NL]; float ww[NL];
#pragma unroll
      for (int g = 0; g < NL; g++) {
        const int j = t + g * RPI + sub;
        ss[g] = __shfl(sj, j); ww[g] = __shfl(w, j);
      }
      uint4 uu[NL];
#pragma unroll
      for (int g = 0; g < NL; g++)
        uu[g] = *(const uint4*)(Hb + (size_t)ss[g] * DOUT + cole);
#pragma unroll
      for (int g = 0; g < NL; g++) {
        const unsigned int vk[4] = {uu[g].x, uu[g].y, uu[g].z, uu[g].w};
#pragma unroll
        for (int k = 0; k < 4; k++) {
          acc[2*k]   += __uint_as_float(vk[k] << 16) * ww[g];
          acc[2*k+1] += __uint_as_float(vk[k] & 0xffff0000u) * ww[g];
        }
      }
    }
    // remainder: RPI rows per step, load predicated so no wasted bytes
    for (; t < cnt; t += RPI) {
      const int j = t + sub;
      const float wr = __shfl(w, j & 63);
      const int   sr = __shfl(sj, j & 63);
      if (j < cnt) {
        const uint4 u = *(const uint4*)(Hb + (size_t)sr * DOUT + cole);
        const unsigned int vk[4] = {u.x, u.y, u.z, u.w};
#pragma unroll
        for (int k = 0; k < 4; k++) {
          acc[2*k]   += __uint_as_float(vk[k] << 16) * wr;
          acc[2*k+1] += __uint_as_float(vk[k] & 0xffff0000u) * wr;
        }
      }
    }
  }

  // reduce edge-weight sum across the wave
#pragma unroll
  for (int off = 32; off; off >>= 1) lsum += __shfl_xor(lsum, off);
  const float inv = 1.f / (lsum + wself);

  // combine the RPI row-accumulators down to lanes [0, LPR)
#pragma unroll
  for (int off = 32; off >= LPR; off >>= 1)
#pragma unroll
    for (int k = 0; k < 8; k++) acc[k] += __shfl_xor(acc[k], off);

  if (lane < LPR) {
    const int c = lane * 8;
    float4 o0, o1;
    o0.x = acc[0] * inv + b[c];     o0.y = acc[1] * inv + b[c + 1];
    o0.z = acc[2] * inv + b[c + 2]; o0.w = acc[3] * inv + b[c + 3];
    o1.x = acc[4] * inv + b[c + 4]; o1.y = acc[5] * inv + b[c + 5];
    o1.z = acc[6] * inv + b[c + 6]; o1.w = acc[7] * inv + b[c + 7];
    *(float4*)(out + (size_t)node * DOUT + c) = o0;
    *(float4*)(out + (size_t)node * DOUT + c + 4) = o1;
  }
}

// column-wise mean over N rows of a [N,64] matrix
__global__ void mean64(const float* __restrict__ Hf, float* __restrict__ out, int N, float scale) {
  __shared__ float sm[256];
  const int col = threadIdx.x & 63;
  const int seg = threadIdx.x >> 6;
  const int stride = gridDim.x * 4;
  float s = 0.f;
  for (int n = blockIdx.x * 4 + seg; n < N; n += stride) s += Hf[(size_t)n * 64 + col];
  sm[threadIdx.x] = s;
  __syncthreads();
  if (seg == 0) {
    float tot = sm[col] + sm[64 + col] + sm[128 + col] + sm[192 + col];
    atomAddF(&out[col], tot * scale);
  }
}

template<int DIN, int DOUT>
static void run_layer(const float* X, const float* Wm, const float* avs, const float* avd,
                      const float* b, const int* rowptr, const int* srcs, int N,
                      unsigned short* Hb, float* OUT, float* Ss, float* Sd, hipStream_t stream) {
  constexpr int TX = DOUT / 4;
  constexpr int ROWS = (256 / TX) * 4;
  gemm_att<DIN, DOUT><<<ceil_div(N, ROWS), 256, 0, stream>>>(X, Wm, avs, avd, Hb, Ss, Sd, N);
  node_gather<DOUT><<<ceil_div((long long)N * 64, 256), 256, 0, stream>>>(
      rowptr, srcs, Ss, Sd, Hb, b, OUT, N);
}

extern "C" void kernel_launch(void* const* d_in, const int* in_sizes, int n_in,
                              void* d_out, int out_size, void* d_ws, size_t ws_size,
                              hipStream_t stream) {
  const float* x   = (const float*)d_in[0];
  const int*   ei  = (const int*)d_in[1];
  const float* W1  = (const float*)d_in[2];
  const float* as1 = (const float*)d_in[3];
  const float* ad1 = (const float*)d_in[4];
  const float* b1  = (const float*)d_in[5];
  const float* W2  = (const float*)d_in[6];
  const float* as2 = (const float*)d_in[7];
  const float* ad2 = (const float*)d_in[8];
  const float* b2  = (const float*)d_in[9];
  const float* W3  = (const float*)d_in[10];
  const float* as3 = (const float*)d_in[11];
  const float* ad3 = (const float*)d_in[12];
  const float* b3  = (const float*)d_in[13];

  const int N = in_sizes[0] / 128;
  const int E = in_sizes[1] / 2;
  const int* src  = ei;
  const int* dstv = ei + E;
  const int NB = ceil_div(N, 1024);

  float* p = (float*)d_ws;
  float* bufA = p; p += (size_t)N * 128;
  float* bufB = p; p += (size_t)N * 128;
  float* Ss   = p; p += N;
  float* Sd   = p; p += N;
  unsigned short* Hb = (unsigned short*)p; p += (size_t)N * 64;  // N*128 bf16
  int* ip = (int*)p;
  int* cnt     = ip; ip += N;
  int* rowptr  = ip; ip += N + 1;
  int* bsum    = ip; ip += NB;
  int* bofs    = ip; ip += NB;
  int* rank    = ip; ip += E;
  int* srcs    = ip; ip += E;

  // ---- CSR build (dst-major), once; reused by all 3 layers ----
  hipMemsetAsync(cnt, 0, (size_t)N * sizeof(int), stream);
  hist_rank<<<ceil_div(E, 256), 256, 0, stream>>>(dstv, cnt, rank, E);
  scan_p1<<<NB, 256, 0, stream>>>(cnt, bsum, N);
  scan_p2<<<1, 1024, 0, stream>>>(bsum, bofs, NB, rowptr + N, E);
  scan_p3<<<NB, 1024, 0, stream>>>(cnt, bofs, rowptr, N);
  scatter_k<<<ceil_div(E, 256), 256, 0, stream>>>(src, dstv, rank, rowptr, srcs, E);

  // ---- 3 GAT layers ----
  run_layer<128, 128>(x,    W1, as1, ad1, b1, rowptr, srcs, N, Hb, bufA, Ss, Sd, stream);
  run_layer<128, 128>(bufA, W2, as2, ad2, b2, rowptr, srcs, N, Hb, bufB, Ss, Sd, stream);
  run_layer<128, 64> (bufB, W3, as3, ad3, b3, rowptr, srcs, N, Hb, bufA, Ss, Sd, stream);

  hipMemsetAsync(d_out, 0, 64 * sizeof(float), stream);
  mean64<<<256, 256, 0, stream>>>(bufA, (float*)d_out, N, 1.0f / (float)N);
}

// Round 5
// 535.499 us; speedup vs baseline: 7.2073x; 1.2423x over previous
//
#include <hip/hip_runtime.h>

static inline int ceil_div(long long a, long long b) { return (int)((a + b - 1) / b); }

typedef __attribute__((ext_vector_type(8))) short bf16x8;
typedef __attribute__((ext_vector_type(4))) float f32x4;

__device__ __forceinline__ float lrelu(float t) { return t > 0.f ? t : 0.2f * t; }

__device__ __forceinline__ void atomAddF(float* p, float v) {
  unsafeAtomicAdd(p, v);  // hardware global_atomic_add_f32
}

// float -> bf16 with round-to-nearest-even
__device__ __forceinline__ unsigned int f2bf(float f) {
  unsigned int u = __float_as_uint(f);
  unsigned int r = ((u >> 16) & 1u) + 0x7fffu;
  return (u + r) >> 16;
}

// ---------------- one-time converts ----------------
__global__ void cvt_bf16(const float* __restrict__ X, unsigned short* __restrict__ Xb, int n4) {
  int i = blockIdx.x * blockDim.x + threadIdx.x;
  if (i < n4) {
    const float4 v = ((const float4*)X)[i];
    uint2 o;
    o.x = f2bf(v.x) | (f2bf(v.y) << 16);
    o.y = f2bf(v.z) | (f2bf(v.w) << 16);
    ((uint2*)Xb)[i] = o;
  }
}

// Wt[n][k] = bf16(W[k][n]);  W is [DIN x DOUTv] row-major
__global__ void transpose_w(const float* __restrict__ W, unsigned short* __restrict__ Wt,
                            int DINv, int DOUTv) {
  int idx = blockIdx.x * blockDim.x + threadIdx.x;
  if (idx < DINv * DOUTv) {
    int k = idx / DOUTv, n = idx % DOUTv;
    Wt[n * DINv + k] = (unsigned short)f2bf(W[idx]);
  }
}

// ---------------- MFMA GEMM + attention scores ----------------
// H = Xb @ W  via D = A(Wt) x B(Xb^T): wave computes 64 W-cols x 64 X-rows.
// A-frag: lane reads Wt[colw0+wt*16+(lane&15)][kk*32+quad*8 .. +7]
// B-frag: lane reads Xb[row0 +xt*16+(lane&15)][kk*32+quad*8 .. +7]
// D tile: lane holds cols n = wt*16+quad*4+reg (4 consecutive!) for X-row m = xt*16+(lane&15)
template<int DOUT>
__launch_bounds__(256)
__global__ void gemm_mfma(const unsigned short* __restrict__ Xb, const unsigned short* __restrict__ Wt,
                          const float* __restrict__ avs, const float* __restrict__ avd,
                          unsigned short* __restrict__ Hb, float* __restrict__ Ss,
                          float* __restrict__ Sd, int N, int RG) {
  constexpr int DIN = 128;
  constexpr int CG = DOUT / 64;
  const int wave = (int)((blockIdx.x * (unsigned)blockDim.x + threadIdx.x) >> 6);
  const int rg = wave / CG;
  const int cg = wave % CG;
  if (rg >= RG) return;
  const int lane = threadIdx.x & 63;
  const int l16 = lane & 15, quad = lane >> 4;
  const int row0 = rg * 64, colw0 = cg * 64;

  int xoff[4], woff[4];
#pragma unroll
  for (int t = 0; t < 4; t++) {
    int m = row0 + t * 16 + l16; if (m > N - 1) m = N - 1;
    xoff[t] = m * DIN + quad * 8;
    woff[t] = (colw0 + t * 16 + l16) * DIN + quad * 8;
  }

  f32x4 acc[4][4];  // [wt][xt]
#pragma unroll
  for (int a = 0; a < 4; a++)
#pragma unroll
    for (int c = 0; c < 4; c++) acc[a][c] = (f32x4)0.f;

#pragma unroll
  for (int kk = 0; kk < 4; kk++) {
    bf16x8 aw[4], bx[4];
#pragma unroll
    for (int t = 0; t < 4; t++) aw[t] = *(const bf16x8*)(Wt + woff[t] + kk * 32);
#pragma unroll
    for (int t = 0; t < 4; t++) bx[t] = *(const bf16x8*)(Xb + xoff[t] + kk * 32);
#pragma unroll
    for (int wt = 0; wt < 4; wt++)
#pragma unroll
      for (int xt = 0; xt < 4; xt++)
        acc[wt][xt] = __builtin_amdgcn_mfma_f32_16x16x32_bf16(aw[wt], bx[xt], acc[wt][xt], 0, 0, 0);
  }

  // epilogue: scores + bf16 H store
  float4 af[4], df[4];
#pragma unroll
  for (int wt = 0; wt < 4; wt++) {
    af[wt] = *(const float4*)(avs + colw0 + wt * 16 + quad * 4);
    df[wt] = *(const float4*)(avd + colw0 + wt * 16 + quad * 4);
  }
#pragma unroll
  for (int xt = 0; xt < 4; xt++) {
    const int m = row0 + xt * 16 + l16;
    float ps = 0.f, pd = 0.f;
#pragma unroll
    for (int wt = 0; wt < 4; wt++) {
      const f32x4 c = acc[wt][xt];
      ps += c[0]*af[wt].x + c[1]*af[wt].y + c[2]*af[wt].z + c[3]*af[wt].w;
      pd += c[0]*df[wt].x + c[1]*df[wt].y + c[2]*df[wt].z + c[3]*df[wt].w;
    }
    ps += __shfl_xor(ps, 16); ps += __shfl_xor(ps, 32);
    pd += __shfl_xor(pd, 16); pd += __shfl_xor(pd, 32);
    if (quad == 0 && m < N) { atomAddF(&Ss[m], ps); atomAddF(&Sd[m], pd); }
    if (m < N) {
      unsigned short* hp = Hb + (size_t)m * DOUT + colw0 + quad * 4;
#pragma unroll
      for (int wt = 0; wt < 4; wt++) {
        const f32x4 c = acc[wt][xt];
        uint2 o;
        o.x = f2bf(c[0]) | (f2bf(c[1]) << 16);
        o.y = f2bf(c[2]) | (f2bf(c[3]) << 16);
        *(uint2*)(hp + wt * 16) = o;
      }
    }
  }
}

// ---------------- CSR build ----------------
__global__ void hist_rank(const int* __restrict__ dstv, int* __restrict__ cnt,
                          int* __restrict__ rank, int E) {
  int i = blockIdx.x * blockDim.x + threadIdx.x;
  if (i < E) rank[i] = atomicAdd(&cnt[dstv[i]], 1);
}

__global__ void scan_p1(const int* __restrict__ cnt, int* __restrict__ bsum, int N) {
  __shared__ int sm[256];
  const int b = blockIdx.x;
  int s = 0;
  for (int i = threadIdx.x; i < 1024; i += 256) {
    int idx = b * 1024 + i;
    s += (idx < N) ? cnt[idx] : 0;
  }
  sm[threadIdx.x] = s; __syncthreads();
  for (int off = 128; off; off >>= 1) {
    if (threadIdx.x < off) sm[threadIdx.x] += sm[threadIdx.x + off];
    __syncthreads();
  }
  if (threadIdx.x == 0) bsum[b] = sm[0];
}

__global__ void scan_p2(const int* __restrict__ bsum, int* __restrict__ bofs,
                        int NB, int* __restrict__ rowptr_N, int E) {
  __shared__ int sm[1024];
  const int t = threadIdx.x;
  const int v0 = (t < NB) ? bsum[t] : 0;
  sm[t] = v0; __syncthreads();
  for (int off = 1; off < 1024; off <<= 1) {
    int v = (t >= off) ? sm[t - off] : 0;
    __syncthreads();
    sm[t] += v;
    __syncthreads();
  }
  if (t < NB) bofs[t] = sm[t] - v0;
  if (t == 0) *rowptr_N = E;
}

__global__ void scan_p3(const int* __restrict__ cnt, const int* __restrict__ bofs,
                        int* __restrict__ rowptr, int N) {
  __shared__ int sm[1024];
  const int t = threadIdx.x;
  const int idx = blockIdx.x * 1024 + t;
  const int v = (idx < N) ? cnt[idx] : 0;
  sm[t] = v; __syncthreads();
  for (int off = 1; off < 1024; off <<= 1) {
    int u = (t >= off) ? sm[t - off] : 0;
    __syncthreads();
    sm[t] += u;
    __syncthreads();
  }
  if (idx < N) rowptr[idx] = sm[t] - v + bofs[blockIdx.x];
}

__global__ void scatter_k(const int* __restrict__ src, const int* __restrict__ dstv,
                          const int* __restrict__ rank, const int* __restrict__ rowptr,
                          int* __restrict__ srcs, int E) {
  int i = blockIdx.x * blockDim.x + threadIdx.x;
  if (i < E) srcs[rowptr[dstv[i]] + rank[i]] = src[i];
}

// ---------------- fused per-dst gather (bf16 H) ----------------
// OBF=true: emit bf16 (next layer's GEMM input); OBF=false: emit f32.
template<int DOUT, bool OBF>
__launch_bounds__(256)
__global__ void node_gather(const int* __restrict__ rowptr, const int* __restrict__ srcs,
                            const float* __restrict__ Ss, const float* __restrict__ Sd,
                            const unsigned short* __restrict__ Hb, const float* __restrict__ b,
                            float* __restrict__ out, unsigned short* __restrict__ outb, int N) {
  constexpr int LPR = DOUT / 8;
  constexpr int RPI = 64 / LPR;
  constexpr int MAIN = 16;
  constexpr int NL = MAIN / RPI;
  const int lane = threadIdx.x & 63;
  const int sub  = lane / LPR;
  const int cole = (lane % LPR) * 8;
  const int node = (int)((blockIdx.x * (unsigned)blockDim.x + threadIdx.x) >> 6);
  if (node >= N) return;
  const int r0 = rowptr[node], r1 = rowptr[node + 1];
  const int deg = r1 - r0;
  const float sd = Sd[node];
  const float eself = lrelu(Ss[node] + sd);

  // pass 1: exact segment max
  float m = eself;
  float e_reg = -1e30f; int s_reg = node;
  if (deg <= 64) {
    if (lane < deg) { s_reg = srcs[r0 + lane]; e_reg = lrelu(Ss[s_reg] + sd); }
    float mx = e_reg;
#pragma unroll
    for (int off = 32; off; off >>= 1) mx = fmaxf(mx, __shfl_xor(mx, off));
    m = fmaxf(m, mx);
  } else {
    for (int base0 = 0; base0 < deg; base0 += 64) {
      int j = base0 + lane;
      float ee = -1e30f;
      if (j < deg) { int ss = srcs[r0 + j]; ee = lrelu(Ss[ss] + sd); }
#pragma unroll
      for (int off = 32; off; off >>= 1) ee = fmaxf(ee, __shfl_xor(ee, off));
      m = fmaxf(m, ee);
    }
  }

  // pass 2: weighted gather
  const float wself = __expf(eself - m);
  float acc[8];
#pragma unroll
  for (int k = 0; k < 8; k++) acc[k] = 0.f;
  if (sub == 0) {
    const uint4 u = *(const uint4*)(Hb + (size_t)node * DOUT + cole);
    const unsigned int vk[4] = {u.x, u.y, u.z, u.w};
#pragma unroll
    for (int k = 0; k < 4; k++) {
      acc[2*k]   += __uint_as_float(vk[k] << 16) * wself;
      acc[2*k+1] += __uint_as_float(vk[k] & 0xffff0000u) * wself;
    }
  }
  float lsum = 0.f;

  for (int base0 = 0; base0 < deg; base0 += 64) {
    int sj; float w;
    if (deg <= 64) {
      sj = s_reg;
      w = (lane < deg) ? __expf(e_reg - m) : 0.f;
    } else {
      const int j = base0 + lane;
      if (j < deg) { sj = srcs[r0 + j]; w = __expf(lrelu(Ss[sj] + sd) - m); }
      else         { sj = node; w = 0.f; }
    }
    lsum += w;
    const int cnt = min(64, deg - base0);
    int t = 0;
    for (; t + MAIN <= cnt; t += MAIN) {
      int ss[NL]; float ww[NL];
#pragma unroll
      for (int g = 0; g < NL; g++) {
        const int j = t + g * RPI + sub;
        ss[g] = __shfl(sj, j); ww[g] = __shfl(w, j);
      }
      uint4 uu[NL];
#pragma unroll
      for (int g = 0; g < NL; g++)
        uu[g] = *(const uint4*)(Hb + (size_t)ss[g] * DOUT + cole);
#pragma unroll
      for (int g = 0; g < NL; g++) {
        const unsigned int vk[4] = {uu[g].x, uu[g].y, uu[g].z, uu[g].w};
#pragma unroll
        for (int k = 0; k < 4; k++) {
          acc[2*k]   += __uint_as_float(vk[k] << 16) * ww[g];
          acc[2*k+1] += __uint_as_float(vk[k] & 0xffff0000u) * ww[g];
        }
      }
    }
    for (; t < cnt; t += RPI) {
      const int j = t + sub;
      const float wr = __shfl(w, j & 63);
      const int   sr = __shfl(sj, j & 63);
      if (j < cnt) {
        const uint4 u = *(const uint4*)(Hb + (size_t)sr * DOUT + cole);
        const unsigned int vk[4] = {u.x, u.y, u.z, u.w};
#pragma unroll
        for (int k = 0; k < 4; k++) {
          acc[2*k]   += __uint_as_float(vk[k] << 16) * wr;
          acc[2*k+1] += __uint_as_float(vk[k] & 0xffff0000u) * wr;
        }
      }
    }
  }

#pragma unroll
  for (int off = 32; off; off >>= 1) lsum += __shfl_xor(lsum, off);
  const float inv = 1.f / (lsum + wself);

#pragma unroll
  for (int off = 32; off >= LPR; off >>= 1)
#pragma unroll
    for (int k = 0; k < 8; k++) acc[k] += __shfl_xor(acc[k], off);

  if (lane < LPR) {
    const int c = lane * 8;
    float o[8];
#pragma unroll
    for (int k = 0; k < 8; k++) o[k] = acc[k] * inv + b[c + k];
    if (OBF) {
      uint4 u;
      u.x = f2bf(o[0]) | (f2bf(o[1]) << 16);
      u.y = f2bf(o[2]) | (f2bf(o[3]) << 16);
      u.z = f2bf(o[4]) | (f2bf(o[5]) << 16);
      u.w = f2bf(o[6]) | (f2bf(o[7]) << 16);
      *(uint4*)(outb + (size_t)node * DOUT + c) = u;
    } else {
      *(float4*)(out + (size_t)node * DOUT + c)     = make_float4(o[0], o[1], o[2], o[3]);
      *(float4*)(out + (size_t)node * DOUT + c + 4) = make_float4(o[4], o[5], o[6], o[7]);
    }
  }
}

// column-wise mean over N rows of a [N,64] matrix
__global__ void mean64(const float* __restrict__ Hf, float* __restrict__ out, int N, float scale) {
  __shared__ float sm[256];
  const int col = threadIdx.x & 63;
  const int seg = threadIdx.x >> 6;
  const int stride = gridDim.x * 4;
  float s = 0.f;
  for (int n = blockIdx.x * 4 + seg; n < N; n += stride) s += Hf[(size_t)n * 64 + col];
  sm[threadIdx.x] = s;
  __syncthreads();
  if (seg == 0) {
    float tot = sm[col] + sm[64 + col] + sm[128 + col] + sm[192 + col];
    atomAddF(&out[col], tot * scale);
  }
}

extern "C" void kernel_launch(void* const* d_in, const int* in_sizes, int n_in,
                              void* d_out, int out_size, void* d_ws, size_t ws_size,
                              hipStream_t stream) {
  const float* x   = (const float*)d_in[0];
  const int*   ei  = (const int*)d_in[1];
  const float* W1  = (const float*)d_in[2];
  const float* as1 = (const float*)d_in[3];
  const float* ad1 = (const float*)d_in[4];
  const float* b1  = (const float*)d_in[5];
  const float* W2  = (const float*)d_in[6];
  const float* as2 = (const float*)d_in[7];
  const float* ad2 = (const float*)d_in[8];
  const float* b2  = (const float*)d_in[9];
  const float* W3  = (const float*)d_in[10];
  const float* as3 = (const float*)d_in[11];
  const float* ad3 = (const float*)d_in[12];
  const float* b3  = (const float*)d_in[13];

  const int N = in_sizes[0] / 128;
  const int E = in_sizes[1] / 2;
  const int* src  = ei;
  const int* dstv = ei + E;
  const int NB = ceil_div(N, 1024);
  const int RG = ceil_div(N, 64);

  float* p = (float*)d_ws;
  float* bufA = p; p += (size_t)N * 64;                            // f32 [N,64] (layer-3 out)
  float* SsSd = p; p += (size_t)2 * N;
  float* Ss = SsSd, *Sd = SsSd + N;
  unsigned short* Xb = (unsigned short*)p; p += (size_t)N * 64;    // bf16 [N,128]
  unsigned short* Hb = (unsigned short*)p; p += (size_t)N * 64;    // bf16 [N,128]
  unsigned short* Wt1 = (unsigned short*)p; p += 128 * 128 / 2;
  unsigned short* Wt2 = (unsigned short*)p; p += 128 * 128 / 2;
  unsigned short* Wt3 = (unsigned short*)p; p += 128 * 64 / 2;
  int* ip = (int*)p;
  int* cnt     = ip; ip += N;
  int* rowptr  = ip; ip += N + 1;
  int* bsum    = ip; ip += NB;
  int* bofs    = ip; ip += NB;
  int* rank    = ip; ip += E;
  int* srcs    = ip; ip += E;

  // ---- CSR build (dst-major), once ----
  hipMemsetAsync(cnt, 0, (size_t)N * sizeof(int), stream);
  hist_rank<<<ceil_div(E, 256), 256, 0, stream>>>(dstv, cnt, rank, E);
  scan_p1<<<NB, 256, 0, stream>>>(cnt, bsum, N);
  scan_p2<<<1, 1024, 0, stream>>>(bsum, bofs, NB, rowptr + N, E);
  scan_p3<<<NB, 1024, 0, stream>>>(cnt, bofs, rowptr, N);
  scatter_k<<<ceil_div(E, 256), 256, 0, stream>>>(src, dstv, rank, rowptr, srcs, E);

  // ---- weight transposes + input convert ----
  transpose_w<<<ceil_div(128 * 128, 256), 256, 0, stream>>>(W1, Wt1, 128, 128);
  transpose_w<<<ceil_div(128 * 128, 256), 256, 0, stream>>>(W2, Wt2, 128, 128);
  transpose_w<<<ceil_div(128 * 64, 256), 256, 0, stream>>>(W3, Wt3, 128, 64);
  cvt_bf16<<<ceil_div((long long)N * 32, 256), 256, 0, stream>>>(x, Xb, N * 32);

  // ---- layer 1 ----
  hipMemsetAsync(SsSd, 0, (size_t)2 * N * sizeof(float), stream);
  gemm_mfma<128><<<ceil_div((long long)RG * 2, 4), 256, 0, stream>>>(Xb, Wt1, as1, ad1, Hb, Ss, Sd, N, RG);
  node_gather<128, true><<<ceil_div((long long)N * 64, 256), 256, 0, stream>>>(
      rowptr, srcs, Ss, Sd, Hb, b1, nullptr, Xb, N);
  // ---- layer 2 ----
  hipMemsetAsync(SsSd, 0, (size_t)2 * N * sizeof(float), stream);
  gemm_mfma<128><<<ceil_div((long long)RG * 2, 4), 256, 0, stream>>>(Xb, Wt2, as2, ad2, Hb, Ss, Sd, N, RG);
  node_gather<128, true><<<ceil_div((long long)N * 64, 256), 256, 0, stream>>>(
      rowptr, srcs, Ss, Sd, Hb, b2, nullptr, Xb, N);
  // ---- layer 3 ----
  hipMemsetAsync(SsSd, 0, (size_t)2 * N * sizeof(float), stream);
  gemm_mfma<64><<<ceil_div((long long)RG, 4), 256, 0, stream>>>(Xb, Wt3, as3, ad3, Hb, Ss, Sd, N, RG);
  node_gather<64, false><<<ceil_div((long long)N * 64, 256), 256, 0, stream>>>(
      rowptr, srcs, Ss, Sd, Hb, b3, bufA, nullptr, N);

  hipMemsetAsync(d_out, 0, 64 * sizeof(float), stream);
  mean64<<<256, 256, 0, stream>>>(bufA, (float*)d_out, N, 1.0f / (float)N);
}

// Round 6
// 488.154 us; speedup vs baseline: 7.9063x; 1.0970x over previous
//
#include <hip/hip_runtime.h>

static inline int ceil_div(long long a, long long b) { return (int)((a + b - 1) / b); }

typedef __attribute__((ext_vector_type(8))) short bf16x8;
typedef __attribute__((ext_vector_type(4))) float f32x4;

__device__ __forceinline__ float lrelu(float t) { return t > 0.f ? t : 0.2f * t; }

__device__ __forceinline__ void atomAddF(float* p, float v) {
  unsafeAtomicAdd(p, v);  // hardware global_atomic_add_f32
}

// float -> bf16 with round-to-nearest-even
__device__ __forceinline__ unsigned int f2bf(float f) {
  unsigned int u = __float_as_uint(f);
  unsigned int r = ((u >> 16) & 1u) + 0x7fffu;
  return (u + r) >> 16;
}

// ---------------- one-time converts ----------------
__global__ void cvt_bf16(const float* __restrict__ X, unsigned short* __restrict__ Xb, int n4) {
  int i = blockIdx.x * blockDim.x + threadIdx.x;
  if (i < n4) {
    const float4 v = ((const float4*)X)[i];
    uint2 o;
    o.x = f2bf(v.x) | (f2bf(v.y) << 16);
    o.y = f2bf(v.z) | (f2bf(v.w) << 16);
    ((uint2*)Xb)[i] = o;
  }
}

__global__ void transpose_w(const float* __restrict__ W, unsigned short* __restrict__ Wt,
                            int DINv, int DOUTv) {
  int idx = blockIdx.x * blockDim.x + threadIdx.x;
  if (idx < DINv * DOUTv) {
    int k = idx / DOUTv, n = idx % DOUTv;
    Wt[n * DINv + k] = (unsigned short)f2bf(W[idx]);
  }
}

// ---------------- MFMA GEMM + attention scores (unchanged from R5) ----------------
template<int DOUT>
__launch_bounds__(256)
__global__ void gemm_mfma(const unsigned short* __restrict__ Xb, const unsigned short* __restrict__ Wt,
                          const float* __restrict__ avs, const float* __restrict__ avd,
                          unsigned short* __restrict__ Hb, float* __restrict__ Ss,
                          float* __restrict__ Sd, int N, int RG) {
  constexpr int DIN = 128;
  constexpr int CG = DOUT / 64;
  const int wave = (int)((blockIdx.x * (unsigned)blockDim.x + threadIdx.x) >> 6);
  const int rg = wave / CG;
  const int cg = wave % CG;
  if (rg >= RG) return;
  const int lane = threadIdx.x & 63;
  const int l16 = lane & 15, quad = lane >> 4;
  const int row0 = rg * 64, colw0 = cg * 64;

  int xoff[4], woff[4];
#pragma unroll
  for (int t = 0; t < 4; t++) {
    int m = row0 + t * 16 + l16; if (m > N - 1) m = N - 1;
    xoff[t] = m * DIN + quad * 8;
    woff[t] = (colw0 + t * 16 + l16) * DIN + quad * 8;
  }

  f32x4 acc[4][4];
#pragma unroll
  for (int a = 0; a < 4; a++)
#pragma unroll
    for (int c = 0; c < 4; c++) acc[a][c] = (f32x4)0.f;

#pragma unroll
  for (int kk = 0; kk < 4; kk++) {
    bf16x8 aw[4], bx[4];
#pragma unroll
    for (int t = 0; t < 4; t++) aw[t] = *(const bf16x8*)(Wt + woff[t] + kk * 32);
#pragma unroll
    for (int t = 0; t < 4; t++) bx[t] = *(const bf16x8*)(Xb + xoff[t] + kk * 32);
#pragma unroll
    for (int wt = 0; wt < 4; wt++)
#pragma unroll
      for (int xt = 0; xt < 4; xt++)
        acc[wt][xt] = __builtin_amdgcn_mfma_f32_16x16x32_bf16(aw[wt], bx[xt], acc[wt][xt], 0, 0, 0);
  }

  float4 af[4], df[4];
#pragma unroll
  for (int wt = 0; wt < 4; wt++) {
    af[wt] = *(const float4*)(avs + colw0 + wt * 16 + quad * 4);
    df[wt] = *(const float4*)(avd + colw0 + wt * 16 + quad * 4);
  }
#pragma unroll
  for (int xt = 0; xt < 4; xt++) {
    const int m = row0 + xt * 16 + l16;
    float ps = 0.f, pd = 0.f;
#pragma unroll
    for (int wt = 0; wt < 4; wt++) {
      const f32x4 c = acc[wt][xt];
      ps += c[0]*af[wt].x + c[1]*af[wt].y + c[2]*af[wt].z + c[3]*af[wt].w;
      pd += c[0]*df[wt].x + c[1]*df[wt].y + c[2]*df[wt].z + c[3]*df[wt].w;
    }
    ps += __shfl_xor(ps, 16); ps += __shfl_xor(ps, 32);
    pd += __shfl_xor(pd, 16); pd += __shfl_xor(pd, 32);
    if (quad == 0 && m < N) { atomAddF(&Ss[m], ps); atomAddF(&Sd[m], pd); }
    if (m < N) {
      unsigned short* hp = Hb + (size_t)m * DOUT + colw0 + quad * 4;
#pragma unroll
      for (int wt = 0; wt < 4; wt++) {
        const f32x4 c = acc[wt][xt];
        uint2 o;
        o.x = f2bf(c[0]) | (f2bf(c[1]) << 16);
        o.y = f2bf(c[2]) | (f2bf(c[3]) << 16);
        *(uint2*)(hp + wt * 16) = o;
      }
    }
  }
}

// ---------------- CSR build ----------------
__global__ void hist_rank(const int* __restrict__ dstv, int* __restrict__ cnt,
                          int* __restrict__ rank, int E) {
  int i = blockIdx.x * blockDim.x + threadIdx.x;
  if (i < E) rank[i] = atomicAdd(&cnt[dstv[i]], 1);
}

__global__ void scan_p1(const int* __restrict__ cnt, int* __restrict__ bsum, int N) {
  __shared__ int sm[256];
  const int b = blockIdx.x;
  int s = 0;
  for (int i = threadIdx.x; i < 1024; i += 256) {
    int idx = b * 1024 + i;
    s += (idx < N) ? cnt[idx] : 0;
  }
  sm[threadIdx.x] = s; __syncthreads();
  for (int off = 128; off; off >>= 1) {
    if (threadIdx.x < off) sm[threadIdx.x] += sm[threadIdx.x + off];
    __syncthreads();
  }
  if (threadIdx.x == 0) bsum[b] = sm[0];
}

__global__ void scan_p2(const int* __restrict__ bsum, int* __restrict__ bofs,
                        int NB, int* __restrict__ rowptr_N, int E) {
  __shared__ int sm[1024];
  const int t = threadIdx.x;
  const int v0 = (t < NB) ? bsum[t] : 0;
  sm[t] = v0; __syncthreads();
  for (int off = 1; off < 1024; off <<= 1) {
    int v = (t >= off) ? sm[t - off] : 0;
    __syncthreads();
    sm[t] += v;
    __syncthreads();
  }
  if (t < NB) bofs[t] = sm[t] - v0;
  if (t == 0) *rowptr_N = E;
}

__global__ void scan_p3(const int* __restrict__ cnt, const int* __restrict__ bofs,
                        int* __restrict__ rowptr, int N) {
  __shared__ int sm[1024];
  const int t = threadIdx.x;
  const int idx = blockIdx.x * 1024 + t;
  const int v = (idx < N) ? cnt[idx] : 0;
  sm[t] = v; __syncthreads();
  for (int off = 1; off < 1024; off <<= 1) {
    int u = (t >= off) ? sm[t - off] : 0;
    __syncthreads();
    sm[t] += u;
    __syncthreads();
  }
  if (idx < N) rowptr[idx] = sm[t] - v + bofs[blockIdx.x];
}

__global__ void scatter_k(const int* __restrict__ src, const int* __restrict__ dstv,
                          const int* __restrict__ rank, const int* __restrict__ rowptr,
                          int* __restrict__ srcs, int E) {
  int i = blockIdx.x * blockDim.x + threadIdx.x;
  if (i < E) srcs[rowptr[dstv[i]] + rank[i]] = src[i];
}

// ---------------- fused per-dst gather: 16 lanes per node, 16 nodes per block ----------
// Each lane owns EPL=DOUT/16 feature columns end-to-end: no cross-lane acc combines.
// Edge metadata (src, w) staged in LDS (cap 64/node); inner loop = broadcast ds_read_b64
// + one row load + unpack/FMA.  OBF=true -> bf16 output, else f32.
template<int DOUT, bool OBF>
__launch_bounds__(256)
__global__ void node_gather(const int* __restrict__ rowptr, const int* __restrict__ srcs,
                            const float* __restrict__ Ss, const float* __restrict__ Sd,
                            const unsigned short* __restrict__ Hb, const float* __restrict__ b,
                            float* __restrict__ out, unsigned short* __restrict__ outb, int N) {
  constexpr int EPL = DOUT / 16;          // bf16 elems per lane (8 or 4)
  constexpr int CAP = 64;                 // LDS-staged edges per node
  __shared__ uint2 swL[16][CAP];          // (src, w_bits) per node-slot

  const int l16 = threadIdx.x & 15;
  const int grp = threadIdx.x >> 4;       // 0..15: node slot in block
  const int node = blockIdx.x * 16 + grp;
  if (node >= N) return;

  const int r0 = rowptr[node], r1 = rowptr[node + 1];
  const int deg = r1 - r0;
  const int degc = min(deg, CAP);
  const float sd = Sd[node];
  const float eself = lrelu(Ss[node] + sd);

  // ---- phase A: load src, compute e, stash (s, e); running max ----
  float m = eself;
  for (int j0 = 0; j0 < deg; j0 += 16) {
    const int idx = j0 + l16;
    float e = -1e30f;
    if (idx < deg) {
      const int s = srcs[r0 + idx];
      e = lrelu(Ss[s] + sd);
      if (idx < CAP) swL[grp][idx] = make_uint2((unsigned)s, __float_as_uint(e));
    }
    m = fmaxf(m, e);
  }
#pragma unroll
  for (int off = 8; off; off >>= 1) m = fmaxf(m, __shfl_xor(m, off));

  // ---- phase A2: w = exp(e - m), write back; per-lane lsum ----
  const float wself = __expf(eself - m);
  float lsum = 0.f;
  for (int j0 = 0; j0 < degc; j0 += 16) {
    const int idx = j0 + l16;
    if (idx < degc) {
      uint2 sw = swL[grp][idx];
      const float w = __expf(__uint_as_float(sw.y) - m);
      sw.y = __float_as_uint(w);
      swL[grp][idx] = sw;
      lsum += w;
    }
  }
  for (int j0 = CAP; j0 < deg; j0 += 16) {   // overflow (rare): just sum w
    const int idx = j0 + l16;
    if (idx < deg) {
      const int s = srcs[r0 + idx];
      lsum += __expf(lrelu(Ss[s] + sd) - m);
    }
  }
#pragma unroll
  for (int off = 8; off; off >>= 1) lsum += __shfl_xor(lsum, off);
  const float inv = 1.f / (lsum + wself);
  __syncthreads();   // swL visible to whole group (same wave: cheap)

  // ---- phase B: weighted gather ----
  float acc[EPL];
#pragma unroll
  for (int k = 0; k < EPL; k++) acc[k] = 0.f;

  const size_t colb = (size_t)l16 * EPL;
  int j = 0;
  for (; j + 4 <= degc; j += 4) {
    uint2 sw0 = swL[grp][j], sw1 = swL[grp][j+1], sw2 = swL[grp][j+2], sw3 = swL[grp][j+3];
    const unsigned short* p0 = Hb + (size_t)sw0.x * DOUT + colb;
    const unsigned short* p1 = Hb + (size_t)sw1.x * DOUT + colb;
    const unsigned short* p2 = Hb + (size_t)sw2.x * DOUT + colb;
    const unsigned short* p3 = Hb + (size_t)sw3.x * DOUT + colb;
    if (EPL == 8) {
      const uint4 u0 = *(const uint4*)p0, u1 = *(const uint4*)p1;
      const uint4 u2 = *(const uint4*)p2, u3 = *(const uint4*)p3;
      const float w0 = __uint_as_float(sw0.y), w1 = __uint_as_float(sw1.y);
      const float w2 = __uint_as_float(sw2.y), w3 = __uint_as_float(sw3.y);
      const unsigned int a0[4] = {u0.x,u0.y,u0.z,u0.w}, a1[4] = {u1.x,u1.y,u1.z,u1.w};
      const unsigned int a2[4] = {u2.x,u2.y,u2.z,u2.w}, a3[4] = {u3.x,u3.y,u3.z,u3.w};
#pragma unroll
      for (int k = 0; k < 4; k++) {
        acc[2*k]   += __uint_as_float(a0[k] << 16) * w0 + __uint_as_float(a1[k] << 16) * w1
                    + __uint_as_float(a2[k] << 16) * w2 + __uint_as_float(a3[k] << 16) * w3;
        acc[2*k+1] += __uint_as_float(a0[k] & 0xffff0000u) * w0 + __uint_as_float(a1[k] & 0xffff0000u) * w1
                    + __uint_as_float(a2[k] & 0xffff0000u) * w2 + __uint_as_float(a3[k] & 0xffff0000u) * w3;
      }
    } else {
      const uint2 u0 = *(const uint2*)p0, u1 = *(const uint2*)p1;
      const uint2 u2 = *(const uint2*)p2, u3 = *(const uint2*)p3;
      const float w0 = __uint_as_float(sw0.y), w1 = __uint_as_float(sw1.y);
      const float w2 = __uint_as_float(sw2.y), w3 = __uint_as_float(sw3.y);
      const unsigned int a0[2] = {u0.x,u0.y}, a1[2] = {u1.x,u1.y};
      const unsigned int a2[2] = {u2.x,u2.y}, a3[2] = {u3.x,u3.y};
#pragma unroll
      for (int k = 0; k < 2; k++) {
        acc[2*k]   += __uint_as_float(a0[k] << 16) * w0 + __uint_as_float(a1[k] << 16) * w1
                    + __uint_as_float(a2[k] << 16) * w2 + __uint_as_float(a3[k] << 16) * w3;
        acc[2*k+1] += __uint_as_float(a0[k] & 0xffff0000u) * w0 + __uint_as_float(a1[k] & 0xffff0000u) * w1
                    + __uint_as_float(a2[k] & 0xffff0000u) * w2 + __uint_as_float(a3[k] & 0xffff0000u) * w3;
      }
    }
  }
  for (; j < degc; j++) {
    const uint2 sw = swL[grp][j];
    const float w = __uint_as_float(sw.y);
    const unsigned short* pp = Hb + (size_t)sw.x * DOUT + colb;
#pragma unroll
    for (int k = 0; k < EPL / 2; k++) {
      const unsigned int u = ((const unsigned int*)pp)[k];
      acc[2*k]   += __uint_as_float(u << 16) * w;
      acc[2*k+1] += __uint_as_float(u & 0xffff0000u) * w;
    }
  }
  // overflow edges (deg > CAP): recompute w from global (rare)
  for (j = CAP; j < deg; j++) {
    const int s = srcs[r0 + j];
    const float w = __expf(lrelu(Ss[s] + sd) - m);
    const unsigned short* pp = Hb + (size_t)s * DOUT + colb;
#pragma unroll
    for (int k = 0; k < EPL / 2; k++) {
      const unsigned int u = ((const unsigned int*)pp)[k];
      acc[2*k]   += __uint_as_float(u << 16) * w;
      acc[2*k+1] += __uint_as_float(u & 0xffff0000u) * w;
    }
  }
  // self contribution
  {
    const unsigned short* pp = Hb + (size_t)node * DOUT + colb;
#pragma unroll
    for (int k = 0; k < EPL / 2; k++) {
      const unsigned int u = ((const unsigned int*)pp)[k];
      acc[2*k]   += __uint_as_float(u << 16) * wself;
      acc[2*k+1] += __uint_as_float(u & 0xffff0000u) * wself;
    }
  }

  // epilogue
  float o[EPL];
#pragma unroll
  for (int k = 0; k < EPL; k++) o[k] = acc[k] * inv + b[colb + k];
  if (OBF) {
    if (EPL == 8) {
      uint4 u;
      u.x = f2bf(o[0]) | (f2bf(o[1]) << 16);
      u.y = f2bf(o[2]) | (f2bf(o[3]) << 16);
      u.z = f2bf(o[4]) | (f2bf(o[5]) << 16);
      u.w = f2bf(o[6]) | (f2bf(o[7]) << 16);
      *(uint4*)(outb + (size_t)node * DOUT + colb) = u;
    } else {
      uint2 u;
      u.x = f2bf(o[0]) | (f2bf(o[1]) << 16);
      u.y = f2bf(o[2]) | (f2bf(o[3]) << 16);
      *(uint2*)(outb + (size_t)node * DOUT + colb) = u;
    }
  } else {
    float* op = out + (size_t)node * DOUT + colb;
#pragma unroll
    for (int k = 0; k < EPL; k += 4)
      *(float4*)(op + k) = make_float4(o[k], o[k+1], o[k+2], o[k+3]);
  }
}

// column-wise mean over N rows of a [N,64] matrix
__global__ void mean64(const float* __restrict__ Hf, float* __restrict__ out, int N, float scale) {
  __shared__ float sm[256];
  const int col = threadIdx.x & 63;
  const int seg = threadIdx.x >> 6;
  const int stride = gridDim.x * 4;
  float s = 0.f;
  for (int n = blockIdx.x * 4 + seg; n < N; n += stride) s += Hf[(size_t)n * 64 + col];
  sm[threadIdx.x] = s;
  __syncthreads();
  if (seg == 0) {
    float tot = sm[col] + sm[64 + col] + sm[128 + col] + sm[192 + col];
    atomAddF(&out[col], tot * scale);
  }
}

extern "C" void kernel_launch(void* const* d_in, const int* in_sizes, int n_in,
                              void* d_out, int out_size, void* d_ws, size_t ws_size,
                              hipStream_t stream) {
  const float* x   = (const float*)d_in[0];
  const int*   ei  = (const int*)d_in[1];
  const float* W1  = (const float*)d_in[2];
  const float* as1 = (const float*)d_in[3];
  const float* ad1 = (const float*)d_in[4];
  const float* b1  = (const float*)d_in[5];
  const float* W2  = (const float*)d_in[6];
  const float* as2 = (const float*)d_in[7];
  const float* ad2 = (const float*)d_in[8];
  const float* b2  = (const float*)d_in[9];
  const float* W3  = (const float*)d_in[10];
  const float* as3 = (const float*)d_in[11];
  const float* ad3 = (const float*)d_in[12];
  const float* b3  = (const float*)d_in[13];

  const int N = in_sizes[0] / 128;
  const int E = in_sizes[1] / 2;
  const int* src  = ei;
  const int* dstv = ei + E;
  const int NB = ceil_div(N, 1024);
  const int RG = ceil_div(N, 64);

  float* p = (float*)d_ws;
  float* bufA = p; p += (size_t)N * 64;
  float* SsSd = p; p += (size_t)2 * N;
  float* Ss = SsSd, *Sd = SsSd + N;
  unsigned short* Xb = (unsigned short*)p; p += (size_t)N * 64;
  unsigned short* Hb = (unsigned short*)p; p += (size_t)N * 64;
  unsigned short* Wt1 = (unsigned short*)p; p += 128 * 128 / 2;
  unsigned short* Wt2 = (unsigned short*)p; p += 128 * 128 / 2;
  unsigned short* Wt3 = (unsigned short*)p; p += 128 * 64 / 2;
  int* ip = (int*)p;
  int* cnt     = ip; ip += N;
  int* rowptr  = ip; ip += N + 1;
  int* bsum    = ip; ip += NB;
  int* bofs    = ip; ip += NB;
  int* rank    = ip; ip += E;
  int* srcs    = ip; ip += E;

  // ---- CSR build (dst-major), once ----
  hipMemsetAsync(cnt, 0, (size_t)N * sizeof(int), stream);
  hist_rank<<<ceil_div(E, 256), 256, 0, stream>>>(dstv, cnt, rank, E);
  scan_p1<<<NB, 256, 0, stream>>>(cnt, bsum, N);
  scan_p2<<<1, 1024, 0, stream>>>(bsum, bofs, NB, rowptr + N, E);
  scan_p3<<<NB, 1024, 0, stream>>>(cnt, bofs, rowptr, N);
  scatter_k<<<ceil_div(E, 256), 256, 0, stream>>>(src, dstv, rank, rowptr, srcs, E);

  // ---- weight transposes + input convert ----
  transpose_w<<<ceil_div(128 * 128, 256), 256, 0, stream>>>(W1, Wt1, 128, 128);
  transpose_w<<<ceil_div(128 * 128, 256), 256, 0, stream>>>(W2, Wt2, 128, 128);
  transpose_w<<<ceil_div(128 * 64, 256), 256, 0, stream>>>(W3, Wt3, 128, 64);
  cvt_bf16<<<ceil_div((long long)N * 32, 256), 256, 0, stream>>>(x, Xb, N * 32);

  const int GG = ceil_div(N, 16);
  // ---- layer 1 ----
  hipMemsetAsync(SsSd, 0, (size_t)2 * N * sizeof(float), stream);
  gemm_mfma<128><<<ceil_div((long long)RG * 2, 4), 256, 0, stream>>>(Xb, Wt1, as1, ad1, Hb, Ss, Sd, N, RG);
  node_gather<128, true><<<GG, 256, 0, stream>>>(rowptr, srcs, Ss, Sd, Hb, b1, nullptr, Xb, N);
  // ---- layer 2 ----
  hipMemsetAsync(SsSd, 0, (size_t)2 * N * sizeof(float), stream);
  gemm_mfma<128><<<ceil_div((long long)RG * 2, 4), 256, 0, stream>>>(Xb, Wt2, as2, ad2, Hb, Ss, Sd, N, RG);
  node_gather<128, true><<<GG, 256, 0, stream>>>(rowptr, srcs, Ss, Sd, Hb, b2, nullptr, Xb, N);
  // ---- layer 3 ----
  hipMemsetAsync(SsSd, 0, (size_t)2 * N * sizeof(float), stream);
  gemm_mfma<64><<<ceil_div((long long)RG, 4), 256, 0, stream>>>(Xb, Wt3, as3, ad3, Hb, Ss, Sd, N, RG);
  node_gather<64, false><<<GG, 256, 0, stream>>>(rowptr, srcs, Ss, Sd, Hb, b3, bufA, nullptr, N);

  hipMemsetAsync(d_out, 0, 64 * sizeof(float), stream);
  mean64<<<256, 256, 0, stream>>>(bufA, (float*)d_out, N, 1.0f / (float)N);
}